// Round 1
// baseline (1342.748 us; speedup 1.0000x reference)
//
#include <hip/hip_runtime.h>

#define L_SEQ 512
#define BATCH 2
#define NROWS (BATCH*L_SEQ)   // 1024
#define DMODEL 512
#define DINNER 1024
#define DSTATE 128
#define NHEADSM 16
#define CONVD 1280
#define DINPROJ 2320

// ws float offsets (after 256B header holding the dtype flag)
#define W_CONVW 0
#define W_CONVB 10240
#define W_DTB   12800
#define W_ALOG  12832
#define W_DD    12864
#define W_RMSW  12896
#define W_LNW   14944
#define W_LNB   15968
#define W_HEADB 16992
#define O_X     18048
#define O_ZX    (O_X  + NROWS*DMODEL)    // 542336
#define O_XC    (O_ZX + NROWS*DINPROJ)   // 2918016
#define O_DT    (O_XC + NROWS*CONVD)     // 4228736
#define O_Y     (O_DT + NROWS*NHEADSM)   // 4245120
#define O_O     (O_Y  + NROWS*DINNER)    // 5293696
// end = 5817984 floats ~ 23.3 MB

__device__ __forceinline__ float b2f(unsigned short h){ return __uint_as_float(((unsigned)h)<<16); }
__device__ __forceinline__ unsigned short f2b(float x){
  unsigned u = __float_as_uint(x);
  return (unsigned short)((u + 0x7fffu + ((u>>16)&1u)) >> 16);
}
__device__ __forceinline__ float loadIn(const void* p, long i, int f){
  return f ? b2f(((const unsigned short*)p)[i]) : ((const float*)p)[i];
}

// ---- dtype detect: low-16 of f32 words are a bf16 value iff data is packed bf16 ----
__global__ void k_detect(const unsigned* __restrict__ emb, int* __restrict__ flag){
  __shared__ int red[256];
  int t = threadIdx.x; int cnt = 0;
  for (int i = 0; i < 16; i++){
    unsigned w = emb[t*16 + i];
    unsigned e = (w >> 7) & 0xffu;           // exponent of the LOW bf16
    cnt += (e >= 100 && e <= 126) ? 1 : 0;
  }
  red[t] = cnt; __syncthreads();
  if (t == 0){
    int s = 0;
    for (int i = 0; i < 256; i++) s += red[i];
    *flag = (s > 2048) ? 1 : 0;              // 4096 samples; bf16 ~ >95%, f32 ~ 10%
  }
}

struct ConvArgs { const void* src[9]; int off[10]; };

__global__ void k_convert(ConvArgs a, const int* __restrict__ flag, float* __restrict__ dst){
  int f = *flag;
  int i = blockIdx.x*256 + threadIdx.x;
  if (i >= a.off[9]) return;
  int s = 0;
  while (i >= a.off[s+1]) s++;
  dst[i] = loadIn(a.src[s], i - a.off[s], f);
}

__global__ void k_embed(const int* __restrict__ tok, const void* __restrict__ emb,
                        const int* __restrict__ flag, float* __restrict__ x){
  int r = blockIdx.x; int f = *flag;
  long base = (long)tok[r] * DMODEL;
  for (int c = threadIdx.x; c < DMODEL; c += 256)
    x[(long)r*DMODEL + c] = loadIn(emb, base + c, f);
}

// C[M,N] = A[M,K] @ B[N,K]^T (+bias). B may be bf16 (flag). outDual: write bf16/f32 per flag.
__global__ __launch_bounds__(256) void k_gemm_nt(
    const float* __restrict__ A, const void* __restrict__ B, long Boff,
    void* __restrict__ Cout, int M, int N, int K,
    const float* __restrict__ bias, const int* __restrict__ flag, int outDual)
{
  int f = *flag;
  __shared__ float As[16][68];
  __shared__ float Bs[16][68];
  int tid = threadIdx.x;
  int tx = tid & 15, ty = tid >> 4;
  int row0 = blockIdx.y*64, col0 = blockIdx.x*64;
  float acc[4][4] = {};
  int c = tid & 15, r0 = tid >> 4;
  for (int k0 = 0; k0 < K; k0 += 16){
    #pragma unroll
    for (int i = 0; i < 4; i++){
      int r = r0 + i*16;
      As[c][r] = A[(long)(row0 + r)*K + k0 + c];
      int n = col0 + r;
      Bs[c][r] = (n < N) ? loadIn(B, Boff + (long)n*K + k0 + c, f) : 0.f;
    }
    __syncthreads();
    #pragma unroll
    for (int kk = 0; kk < 16; kk++){
      float4 av = *(const float4*)&As[kk][ty*4];
      float4 bv = *(const float4*)&Bs[kk][tx*4];
      float aa[4] = {av.x, av.y, av.z, av.w};
      float bb[4] = {bv.x, bv.y, bv.z, bv.w};
      #pragma unroll
      for (int i = 0; i < 4; i++)
        #pragma unroll
        for (int j = 0; j < 4; j++)
          acc[i][j] = fmaf(aa[i], bb[j], acc[i][j]);
    }
    __syncthreads();
  }
  #pragma unroll
  for (int i = 0; i < 4; i++){
    int row = row0 + ty*4 + i;
    #pragma unroll
    for (int j = 0; j < 4; j++){
      int col = col0 + tx*4 + j;
      if (col < N){
        float v = acc[i][j] + (bias ? bias[col] : 0.f);
        long idx = (long)row*N + col;
        if (outDual && f) ((unsigned short*)Cout)[idx] = f2b(v);
        else              ((float*)Cout)[idx] = v;
      }
    }
  }
}

__global__ __launch_bounds__(256) void k_conv_dt(
    const float* __restrict__ zx, const float* __restrict__ cw, const float* __restrict__ cb,
    const float* __restrict__ dtb, float* __restrict__ xc, float* __restrict__ dt)
{
  int r = blockIdx.x; int b = r >> 9, l = r & 511;
  int t = threadIdx.x;
  for (int c = t; c < CONVD; c += 256){
    float s = cb[c];
    #pragma unroll
    for (int k = 0; k < 4; k++){
      int pos = l - 3 + k;
      if (pos >= 0)
        s = fmaf(zx[(long)(b*L_SEQ + pos)*DINPROJ + DINNER + c], cw[c*4 + k], s);
    }
    xc[(long)r*CONVD + c] = s / (1.f + __expf(-s));   // silu
  }
  if (t < NHEADSM){
    float v = zx[(long)r*DINPROJ + DINNER + CONVD + t] + dtb[t];
    dt[r*NHEADSM + t] = (v > 20.f) ? v : log1pf(__expf(v));  // softplus
  }
}

// one block per (b,h); 256 thr; lane group of 4 covers n=0..127 with swizzled float4 mapping
__global__ __launch_bounds__(256) void k_scan(
    const float* __restrict__ xc, const float* __restrict__ dt,
    const float* __restrict__ alog, const float* __restrict__ dvec, float* __restrict__ y)
{
  int b = blockIdx.x >> 4, h = blockIdx.x & 15;
  int t = threadIdx.x, w = t >> 6, lane = t & 63;
  int p = w*16 + (lane >> 2), qp = lane & 3;
  float A  = -__expf(alog[h]);
  float Dv = dvec[h];
  __shared__ float dtl[512], dal[512];
  __shared__ float bc[2][256];
  for (int i = t; i < 512; i += 256){
    float d = dt[(b*L_SEQ + i)*NHEADSM + h];
    dtl[i] = d; dal[i] = __expf(d * A);
  }
  float4 s[8];
  #pragma unroll
  for (int j = 0; j < 8; j++) s[j] = make_float4(0.f,0.f,0.f,0.f);
  int nn[8];
  #pragma unroll
  for (int j = 0; j < 8; j++) nn[j] = qp*8 + ((j + 2*qp) & 7);   // bank-conflict-free rotation
  __syncthreads();
  int xoff = h*64 + p;
  for (int l = 0; l < L_SEQ; l++){
    long rb = (long)(b*L_SEQ + l)*CONVD;
    bc[l & 1][t] = xc[rb + DINNER + t];     // t<128: B, t>=128: C (contiguous cols 1024..1279)
    float xp = xc[rb + xoff];
    __syncthreads();
    float da = dal[l], coef = dtl[l] * xp;
    const float4* Bv = (const float4*)&bc[l & 1][0];
    const float4* Cv = (const float4*)&bc[l & 1][128];
    float acc = 0.f;
    #pragma unroll
    for (int j = 0; j < 8; j++){
      float4 Bx = Bv[nn[j]], Cx = Cv[nn[j]];
      s[j].x = fmaf(s[j].x, da, coef*Bx.x); acc = fmaf(s[j].x, Cx.x, acc);
      s[j].y = fmaf(s[j].y, da, coef*Bx.y); acc = fmaf(s[j].y, Cx.y, acc);
      s[j].z = fmaf(s[j].z, da, coef*Bx.z); acc = fmaf(s[j].z, Cx.z, acc);
      s[j].w = fmaf(s[j].w, da, coef*Bx.w); acc = fmaf(s[j].w, Cx.w, acc);
    }
    acc += __shfl_xor(acc, 1);
    acc += __shfl_xor(acc, 2);
    if (qp == 0)
      y[(long)(b*L_SEQ + l)*DINNER + h*64 + p] = fmaf(Dv, xp, acc);
  }
}

__global__ __launch_bounds__(256) void k_gated_rms(
    float* __restrict__ y, const float* __restrict__ zx, const float* __restrict__ rw)
{
  int r = blockIdx.x, t = threadIdx.x;
  float g[4]; float ss = 0.f;
  #pragma unroll
  for (int i = 0; i < 4; i++){
    int c = t + i*256;
    float z  = zx[(long)r*DINPROJ + c];
    float yv = y[(long)r*DINNER + c];
    float gz = z / (1.f + __expf(-z));
    g[i] = yv * gz;
    ss = fmaf(g[i], g[i], ss);
  }
  #pragma unroll
  for (int o = 1; o < 64; o <<= 1) ss += __shfl_xor(ss, o);
  __shared__ float red[4];
  int w = t >> 6, lane = t & 63;
  if (lane == 0) red[w] = ss;
  __syncthreads();
  float tot = red[0] + red[1] + red[2] + red[3];
  float sc = rsqrtf(tot / (float)DINNER + 1e-5f);
  #pragma unroll
  for (int i = 0; i < 4; i++){
    int c = t + i*256;
    y[(long)r*DINNER + c] = g[i] * sc * rw[c];
  }
}

__global__ __launch_bounds__(256) void k_add_ln(
    float* __restrict__ x, const float* __restrict__ o,
    const float* __restrict__ lw, const float* __restrict__ lb)
{
  int r = blockIdx.x, t = threadIdx.x;
  float v[2]; float sm = 0.f;
  #pragma unroll
  for (int i = 0; i < 2; i++){ int c = t + i*256; v[i] = x[(long)r*DMODEL + c] + o[(long)r*DMODEL + c]; sm += v[i]; }
  #pragma unroll
  for (int off = 1; off < 64; off <<= 1) sm += __shfl_xor(sm, off);
  __shared__ float red[4]; __shared__ float red2[4];
  int w = t >> 6, lane = t & 63;
  if (lane == 0) red[w] = sm;
  __syncthreads();
  float mu = (red[0] + red[1] + red[2] + red[3]) / (float)DMODEL;
  float var = 0.f;
  #pragma unroll
  for (int i = 0; i < 2; i++){ v[i] -= mu; var = fmaf(v[i], v[i], var); }
  #pragma unroll
  for (int off = 1; off < 64; off <<= 1) var += __shfl_xor(var, off);
  if (lane == 0) red2[w] = var;
  __syncthreads();
  float vv = (red2[0] + red2[1] + red2[2] + red2[3]) / (float)DMODEL;
  float sc = rsqrtf(vv + 1e-5f);
  #pragma unroll
  for (int i = 0; i < 2; i++){
    int c = t + i*256;
    x[(long)r*DMODEL + c] = v[i]*sc*lw[c] + lb[c];
  }
}

extern "C" void kernel_launch(void* const* d_in, const int* in_sizes, int n_in,
                              void* d_out, int out_size, void* d_ws, size_t ws_size,
                              hipStream_t stream)
{
  const int* tokens = (const int*)d_in[0];
  const void* emb = d_in[1];
  int* flag = (int*)d_ws;
  float* ws = (float*)((char*)d_ws + 256);

  k_detect<<<1, 256, 0, stream>>>((const unsigned*)emb, flag);

  ConvArgs ca;
  const int sizes[9] = {10240, 2560, 32, 32, 32, 2048, 1024, 1024, 1000};
  const int idxs[9]  = {3, 4, 5, 6, 7, 8, 10, 11, 13};
  int off = 0;
  for (int s = 0; s < 9; s++){ ca.src[s] = d_in[idxs[s]]; ca.off[s] = off; off += sizes[s]; }
  ca.off[9] = off;
  k_convert<<<(off + 255)/256, 256, 0, stream>>>(ca, flag, ws);

  float* X  = ws + O_X;
  float* ZX = ws + O_ZX;
  float* XC = ws + O_XC;
  float* DT = ws + O_DT;
  float* Y  = ws + O_Y;
  float* Ob = ws + O_O;

  k_embed<<<NROWS, 256, 0, stream>>>(tokens, emb, flag, X);

  for (int layer = 0; layer < 2; layer++){
    long wiOff = (long)layer * DINPROJ * DMODEL;
    k_gemm_nt<<<dim3(37, 16), 256, 0, stream>>>(
        X, d_in[2], wiOff, (void*)ZX, NROWS, DINPROJ, DMODEL, (const float*)nullptr, flag, 0);
    k_conv_dt<<<NROWS, 256, 0, stream>>>(
        ZX, ws + W_CONVW + layer*5120, ws + W_CONVB + layer*1280, ws + W_DTB + layer*16, XC, DT);
    k_scan<<<32, 256, 0, stream>>>(
        XC, DT, ws + W_ALOG + layer*16, ws + W_DD + layer*16, Y);
    k_gated_rms<<<NROWS, 256, 0, stream>>>(Y, ZX, ws + W_RMSW + layer*1024);
    long woOff = (long)layer * DMODEL * DINNER;
    k_gemm_nt<<<dim3(8, 16), 256, 0, stream>>>(
        Y, d_in[9], woOff, (void*)Ob, NROWS, DMODEL, DINNER, (const float*)nullptr, flag, 0);
    k_add_ln<<<NROWS, 256, 0, stream>>>(X, Ob, ws + W_LNW + layer*512, ws + W_LNB + layer*512);
  }

  k_gemm_nt<<<dim3(16, 16), 256, 0, stream>>>(
      X, d_in[12], 0L, d_out, NROWS, 1000, DMODEL, ws + W_HEADB, flag, 1);
}

// Round 2
// 751.575 us; speedup vs baseline: 1.7866x; 1.7866x over previous
//
#include <hip/hip_runtime.h>

#define L_SEQ 512
#define BATCH 2
#define NROWS (BATCH*L_SEQ)   // 1024
#define DMODEL 512
#define DINNER 1024
#define DSTATE 128
#define NHEADSM 16
#define CONVD 1280
#define DINPROJ 2320
#define QCH 32                // chunk length
#define NCH 16                // chunks per sequence

// ws float offsets (after 256B header holding the dtype flag)
#define W_CONVW 0
#define W_CONVB 10240
#define W_DTB   12800
#define W_ALOG  12832
#define W_DD    12864
#define W_RMSW  12896
#define W_LNW   14944
#define W_LNB   15968
#define W_HEADB 16992
#define O_X     18048
#define O_ZX    (O_X  + NROWS*DMODEL)    // 542336
#define O_XC    (O_ZX + NROWS*DINPROJ)   // 2918016
#define O_DT    (O_XC + NROWS*CONVD)     // 4228736
#define O_Y     (O_DT + NROWS*NHEADSM)   // 4245120
#define O_O     (O_Y  + NROWS*DINNER)    // 5293696
#define O_LA    (O_O  + NROWS*DMODEL)    // 5817984  (BATCH*NHEADSM*L_SEQ = 16384)
#define O_S     (O_LA + 16384)           // 5834368  (2*16*16*8192 = 4194304)
#define O_H     (O_S  + 4194304)         // 10028672 (same)
// end = 14222976 floats ~ 57 MB

__device__ __forceinline__ float b2f(unsigned short h){ return __uint_as_float(((unsigned)h)<<16); }
__device__ __forceinline__ unsigned short f2b(float x){
  unsigned u = __float_as_uint(x);
  return (unsigned short)((u + 0x7fffu + ((u>>16)&1u)) >> 16);
}
__device__ __forceinline__ float loadIn(const void* p, long i, int f){
  return f ? b2f(((const unsigned short*)p)[i]) : ((const float*)p)[i];
}

// ---- dtype detect: low-16 of f32 words are a bf16 value iff data is packed bf16 ----
__global__ void k_detect(const unsigned* __restrict__ emb, int* __restrict__ flag){
  __shared__ int red[256];
  int t = threadIdx.x; int cnt = 0;
  for (int i = 0; i < 16; i++){
    unsigned w = emb[t*16 + i];
    unsigned e = (w >> 7) & 0xffu;
    cnt += (e >= 100 && e <= 126) ? 1 : 0;
  }
  red[t] = cnt; __syncthreads();
  if (t == 0){
    int s = 0;
    for (int i = 0; i < 256; i++) s += red[i];
    *flag = (s > 2048) ? 1 : 0;
  }
}

struct ConvArgs { const void* src[9]; int off[10]; };

__global__ void k_convert(ConvArgs a, const int* __restrict__ flag, float* __restrict__ dst){
  int f = *flag;
  int i = blockIdx.x*256 + threadIdx.x;
  if (i >= a.off[9]) return;
  int s = 0;
  while (i >= a.off[s+1]) s++;
  dst[i] = loadIn(a.src[s], i - a.off[s], f);
}

__global__ void k_embed(const int* __restrict__ tok, const void* __restrict__ emb,
                        const int* __restrict__ flag, float* __restrict__ x){
  int r = blockIdx.x; int f = *flag;
  long base = (long)tok[r] * DMODEL;
  for (int c = threadIdx.x; c < DMODEL; c += 256)
    x[(long)r*DMODEL + c] = loadIn(emb, base + c, f);
}

// C[M,N] = A[M,K] @ B[N,K]^T (+bias). B may be bf16 (flag). outDual: write bf16/f32 per flag.
__global__ __launch_bounds__(256) void k_gemm_nt(
    const float* __restrict__ A, const void* __restrict__ B, long Boff,
    void* __restrict__ Cout, int M, int N, int K,
    const float* __restrict__ bias, const int* __restrict__ flag, int outDual)
{
  int f = *flag;
  __shared__ float As[16][68];
  __shared__ float Bs[16][68];
  int tid = threadIdx.x;
  int tx = tid & 15, ty = tid >> 4;
  int row0 = blockIdx.y*64, col0 = blockIdx.x*64;
  float acc[4][4] = {};
  int c = tid & 15, r0 = tid >> 4;
  for (int k0 = 0; k0 < K; k0 += 16){
    #pragma unroll
    for (int i = 0; i < 4; i++){
      int r = r0 + i*16;
      As[c][r] = A[(long)(row0 + r)*K + k0 + c];
      int n = col0 + r;
      Bs[c][r] = (n < N) ? loadIn(B, Boff + (long)n*K + k0 + c, f) : 0.f;
    }
    __syncthreads();
    #pragma unroll
    for (int kk = 0; kk < 16; kk++){
      float4 av = *(const float4*)&As[kk][ty*4];
      float4 bv = *(const float4*)&Bs[kk][tx*4];
      float aa[4] = {av.x, av.y, av.z, av.w};
      float bb[4] = {bv.x, bv.y, bv.z, bv.w};
      #pragma unroll
      for (int i = 0; i < 4; i++)
        #pragma unroll
        for (int j = 0; j < 4; j++)
          acc[i][j] = fmaf(aa[i], bb[j], acc[i][j]);
    }
    __syncthreads();
  }
  #pragma unroll
  for (int i = 0; i < 4; i++){
    int row = row0 + ty*4 + i;
    #pragma unroll
    for (int j = 0; j < 4; j++){
      int col = col0 + tx*4 + j;
      if (col < N){
        float v = acc[i][j] + (bias ? bias[col] : 0.f);
        long idx = (long)row*N + col;
        if (outDual && f) ((unsigned short*)Cout)[idx] = f2b(v);
        else              ((float*)Cout)[idx] = v;
      }
    }
  }
}

__global__ __launch_bounds__(256) void k_conv_dt(
    const float* __restrict__ zx, const float* __restrict__ cw, const float* __restrict__ cb,
    const float* __restrict__ dtb, float* __restrict__ xc, float* __restrict__ dt)
{
  int r = blockIdx.x; int b = r >> 9, l = r & 511;
  int t = threadIdx.x;
  for (int c = t; c < CONVD; c += 256){
    float s = cb[c];
    #pragma unroll
    for (int k = 0; k < 4; k++){
      int pos = l - 3 + k;
      if (pos >= 0)
        s = fmaf(zx[(long)(b*L_SEQ + pos)*DINPROJ + DINNER + c], cw[c*4 + k], s);
    }
    xc[(long)r*CONVD + c] = s / (1.f + __expf(-s));   // silu
  }
  if (t < NHEADSM){
    float v = zx[(long)r*DINPROJ + DINNER + CONVD + t] + dtb[t];
    dt[r*NHEADSM + t] = (v > 20.f) ? v : log1pf(__expf(v));  // softplus
  }
}

// ================= chunked SSD scan =================
// chunk1: per (b,h,c): intra-chunk Y (+D*x), chunk state summary S, chunk-local log-decay LA
__global__ __launch_bounds__(256) void k_chunk1(
    const float* __restrict__ xc, const float* __restrict__ dtbuf,
    const float* __restrict__ alog, const float* __restrict__ dvec,
    float* __restrict__ S, float* __restrict__ LAb, float* __restrict__ y)
{
  int c = blockIdx.x, h = blockIdx.y, b = blockIdx.z;
  int t = threadIdx.x;
  int l0 = c*QCH;
  __shared__ float Xs[QCH][68];
  __shared__ float Bs[QCH][132];
  __shared__ float Cs[QCH][132];
  __shared__ float Gs[QCH][33];
  __shared__ float dtl[QCH], lal[QCH], coef[QCH];
  float A  = -__expf(alog[h]);
  float Dv = dvec[h];
  if (t < QCH) dtl[t] = dtbuf[(b*L_SEQ + l0 + t)*NHEADSM + h];
  #pragma unroll
  for (int k = 0; k < 8; k++){
    int idx = t + k*256; int i = idx >> 6, p = idx & 63;
    Xs[i][p] = xc[(long)(b*L_SEQ + l0 + i)*CONVD + h*64 + p];
  }
  #pragma unroll
  for (int k = 0; k < 16; k++){
    int idx = t + k*256; int i = idx >> 7, n = idx & 127;
    long rb = (long)(b*L_SEQ + l0 + i)*CONVD;
    Bs[i][n] = xc[rb + DINNER + n];
    Cs[i][n] = xc[rb + DINNER + DSTATE + n];
  }
  __syncthreads();
  if (t == 0){
    float s = 0.f;
    for (int i = 0; i < QCH; i++){ s += dtl[i]; lal[i] = s*A; }
  }
  __syncthreads();
  if (t < QCH){
    coef[t] = __expf(lal[QCH-1] - lal[t]) * dtl[t];
    LAb[(b*NHEADSM + h)*L_SEQ + l0 + t] = lal[t];
  }
  __syncthreads();
  // ---- S[p][n] = sum_j coef[j] * X[j][p] * B[j][n] ----
  {
    int p = t >> 2, q = t & 3;           // thread: p fixed, n = q*4 + 16k (float4)
    float4 acc[8];
    #pragma unroll
    for (int k = 0; k < 8; k++) acc[k] = make_float4(0.f,0.f,0.f,0.f);
    for (int j = 0; j < QCH; j++){
      float xv = Xs[j][p] * coef[j];
      #pragma unroll
      for (int k = 0; k < 8; k++){
        float4 bv = *(const float4*)&Bs[j][q*4 + 16*k];
        acc[k].x = fmaf(xv, bv.x, acc[k].x);
        acc[k].y = fmaf(xv, bv.y, acc[k].y);
        acc[k].z = fmaf(xv, bv.z, acc[k].z);
        acc[k].w = fmaf(xv, bv.w, acc[k].w);
      }
    }
    long sb = ((long)((b*NHEADSM + h)*NCH + c))*8192 + p*128 + q*4;
    #pragma unroll
    for (int k = 0; k < 8; k++) *(float4*)&S[sb + 16*k] = acc[k];
  }
  // ---- G[i][j] = (j<=i) ? exp(la[i]-la[j])*dt[j]*(C_i . B_j) : 0 ----
  {
    int i = t >> 3, jj = t & 7;
    float acc[4] = {};
    for (int nb = 0; nb < 32; nb++){
      float4 cv = *(const float4*)&Cs[i][nb*4];
      #pragma unroll
      for (int k = 0; k < 4; k++){
        float4 bv = *(const float4*)&Bs[jj + 8*k][nb*4];
        acc[k] += cv.x*bv.x + cv.y*bv.y + cv.z*bv.z + cv.w*bv.w;
      }
    }
    #pragma unroll
    for (int k = 0; k < 4; k++){
      int j = jj + 8*k;
      Gs[i][j] = (j <= i) ? __expf(lal[i] - lal[j]) * dtl[j] * acc[k] : 0.f;
    }
  }
  __syncthreads();
  // ---- Y[i][p] = D*x[i][p] + sum_j G[i][j]*X[j][p] ----
  {
    int i = t >> 3, p0 = (t & 7)*8;
    float4 a0 = *(const float4*)&Xs[i][p0];
    float4 a1 = *(const float4*)&Xs[i][p0+4];
    a0.x *= Dv; a0.y *= Dv; a0.z *= Dv; a0.w *= Dv;
    a1.x *= Dv; a1.y *= Dv; a1.z *= Dv; a1.w *= Dv;
    for (int j = 0; j < QCH; j++){
      float g = Gs[i][j];
      float4 x0 = *(const float4*)&Xs[j][p0];
      float4 x1 = *(const float4*)&Xs[j][p0+4];
      a0.x = fmaf(g, x0.x, a0.x); a0.y = fmaf(g, x0.y, a0.y);
      a0.z = fmaf(g, x0.z, a0.z); a0.w = fmaf(g, x0.w, a0.w);
      a1.x = fmaf(g, x1.x, a1.x); a1.y = fmaf(g, x1.y, a1.y);
      a1.z = fmaf(g, x1.z, a1.z); a1.w = fmaf(g, x1.w, a1.w);
    }
    long yb = (long)(b*L_SEQ + l0 + i)*DINNER + h*64 + p0;
    *(float4*)&y[yb]   = a0;
    *(float4*)&y[yb+4] = a1;
  }
}

// chunk2: serial state propagation across chunks. grid (h, b), 256 thr.
__global__ __launch_bounds__(256) void k_chunk2(
    const float* __restrict__ S, const float* __restrict__ LAb, float* __restrict__ H)
{
  int h = blockIdx.x, b = blockIdx.y;
  int t = threadIdx.x;
  int p = t >> 2, n0 = (t & 3)*32;
  float4 hr[8];
  #pragma unroll
  for (int k = 0; k < 8; k++) hr[k] = make_float4(0.f,0.f,0.f,0.f);
  long base = ((long)((b*NHEADSM + h)*NCH))*8192 + p*128 + n0;
  int laBase = (b*NHEADSM + h)*L_SEQ;
  for (int c = 0; c < NCH; c++){
    long off = base + (long)c*8192;
    #pragma unroll
    for (int k = 0; k < 8; k++) *(float4*)&H[off + 4*k] = hr[k];
    float lam = __expf(LAb[laBase + c*QCH + QCH - 1]);
    #pragma unroll
    for (int k = 0; k < 8; k++){
      float4 sv = *(const float4*)&S[off + 4*k];
      hr[k].x = fmaf(hr[k].x, lam, sv.x);
      hr[k].y = fmaf(hr[k].y, lam, sv.y);
      hr[k].z = fmaf(hr[k].z, lam, sv.z);
      hr[k].w = fmaf(hr[k].w, lam, sv.w);
    }
  }
}

// chunk3: Y += exp(la[i]) * (C_i . H_c[p,:])
__global__ __launch_bounds__(256) void k_chunk3(
    const float* __restrict__ xc, const float* __restrict__ H,
    const float* __restrict__ LAb, float* __restrict__ y)
{
  int c = blockIdx.x, h = blockIdx.y, b = blockIdx.z;
  int t = threadIdx.x, l0 = c*QCH;
  __shared__ float Cs[QCH][132];
  __shared__ float Hs[64][132];
  __shared__ float lal[QCH];
  if (t < QCH) lal[t] = LAb[(b*NHEADSM + h)*L_SEQ + l0 + t];
  #pragma unroll
  for (int k = 0; k < 16; k++){
    int idx = t + k*256; int i = idx >> 7, n = idx & 127;
    Cs[i][n] = xc[(long)(b*L_SEQ + l0 + i)*CONVD + DINNER + DSTATE + n];
  }
  long hb = ((long)((b*NHEADSM + h)*NCH + c))*8192;
  #pragma unroll
  for (int k = 0; k < 32; k++){
    int idx = t + k*256; int p = idx >> 7, n = idx & 127;
    Hs[p][n] = H[hb + idx];
  }
  __syncthreads();
  int i = t >> 3, p0 = (t & 7)*8;
  float acc[8] = {};
  for (int nb = 0; nb < 32; nb++){
    float4 cv = *(const float4*)&Cs[i][nb*4];
    #pragma unroll
    for (int q = 0; q < 8; q++){
      float4 hv = *(const float4*)&Hs[p0 + q][nb*4];
      acc[q] += cv.x*hv.x + cv.y*hv.y + cv.z*hv.z + cv.w*hv.w;
    }
  }
  float e = __expf(lal[i]);
  long yb = (long)(b*L_SEQ + l0 + i)*DINNER + h*64 + p0;
  #pragma unroll
  for (int q = 0; q < 8; q++)
    y[yb + q] = fmaf(e, acc[q], y[yb + q]);
}

__global__ __launch_bounds__(256) void k_gated_rms(
    float* __restrict__ y, const float* __restrict__ zx, const float* __restrict__ rw)
{
  int r = blockIdx.x, t = threadIdx.x;
  float g[4]; float ss = 0.f;
  #pragma unroll
  for (int i = 0; i < 4; i++){
    int c = t + i*256;
    float z  = zx[(long)r*DINPROJ + c];
    float yv = y[(long)r*DINNER + c];
    float gz = z / (1.f + __expf(-z));
    g[i] = yv * gz;
    ss = fmaf(g[i], g[i], ss);
  }
  #pragma unroll
  for (int o = 1; o < 64; o <<= 1) ss += __shfl_xor(ss, o);
  __shared__ float red[4];
  int w = t >> 6, lane = t & 63;
  if (lane == 0) red[w] = ss;
  __syncthreads();
  float tot = red[0] + red[1] + red[2] + red[3];
  float sc = rsqrtf(tot / (float)DINNER + 1e-5f);
  #pragma unroll
  for (int i = 0; i < 4; i++){
    int c = t + i*256;
    y[(long)r*DINNER + c] = g[i] * sc * rw[c];
  }
}

__global__ __launch_bounds__(256) void k_add_ln(
    float* __restrict__ x, const float* __restrict__ o,
    const float* __restrict__ lw, const float* __restrict__ lb)
{
  int r = blockIdx.x, t = threadIdx.x;
  float v[2]; float sm = 0.f;
  #pragma unroll
  for (int i = 0; i < 2; i++){ int c = t + i*256; v[i] = x[(long)r*DMODEL + c] + o[(long)r*DMODEL + c]; sm += v[i]; }
  #pragma unroll
  for (int off = 1; off < 64; off <<= 1) sm += __shfl_xor(sm, off);
  __shared__ float red[4]; __shared__ float red2[4];
  int w = t >> 6, lane = t & 63;
  if (lane == 0) red[w] = sm;
  __syncthreads();
  float mu = (red[0] + red[1] + red[2] + red[3]) / (float)DMODEL;
  float var = 0.f;
  #pragma unroll
  for (int i = 0; i < 2; i++){ v[i] -= mu; var = fmaf(v[i], v[i], var); }
  #pragma unroll
  for (int off = 1; off < 64; off <<= 1) var += __shfl_xor(var, off);
  if (lane == 0) red2[w] = var;
  __syncthreads();
  float vv = (red2[0] + red2[1] + red2[2] + red2[3]) / (float)DMODEL;
  float sc = rsqrtf(vv + 1e-5f);
  #pragma unroll
  for (int i = 0; i < 2; i++){
    int c = t + i*256;
    x[(long)r*DMODEL + c] = v[i]*sc*lw[c] + lb[c];
  }
}

extern "C" void kernel_launch(void* const* d_in, const int* in_sizes, int n_in,
                              void* d_out, int out_size, void* d_ws, size_t ws_size,
                              hipStream_t stream)
{
  const int* tokens = (const int*)d_in[0];
  const void* emb = d_in[1];
  int* flag = (int*)d_ws;
  float* ws = (float*)((char*)d_ws + 256);

  k_detect<<<1, 256, 0, stream>>>((const unsigned*)emb, flag);

  ConvArgs ca;
  const int sizes[9] = {10240, 2560, 32, 32, 32, 2048, 1024, 1024, 1000};
  const int idxs[9]  = {3, 4, 5, 6, 7, 8, 10, 11, 13};
  int off = 0;
  for (int s = 0; s < 9; s++){ ca.src[s] = d_in[idxs[s]]; ca.off[s] = off; off += sizes[s]; }
  ca.off[9] = off;
  k_convert<<<(off + 255)/256, 256, 0, stream>>>(ca, flag, ws);

  float* X  = ws + O_X;
  float* ZX = ws + O_ZX;
  float* XC = ws + O_XC;
  float* DT = ws + O_DT;
  float* Y  = ws + O_Y;
  float* Ob = ws + O_O;
  float* LA = ws + O_LA;
  float* Sb = ws + O_S;
  float* Hb = ws + O_H;

  k_embed<<<NROWS, 256, 0, stream>>>(tokens, emb, flag, X);

  for (int layer = 0; layer < 2; layer++){
    long wiOff = (long)layer * DINPROJ * DMODEL;
    k_gemm_nt<<<dim3(37, 16), 256, 0, stream>>>(
        X, d_in[2], wiOff, (void*)ZX, NROWS, DINPROJ, DMODEL, (const float*)nullptr, flag, 0);
    k_conv_dt<<<NROWS, 256, 0, stream>>>(
        ZX, ws + W_CONVW + layer*5120, ws + W_CONVB + layer*1280, ws + W_DTB + layer*16, XC, DT);
    k_chunk1<<<dim3(NCH, NHEADSM, BATCH), 256, 0, stream>>>(
        XC, DT, ws + W_ALOG + layer*16, ws + W_DD + layer*16, Sb, LA, Y);
    k_chunk2<<<dim3(NHEADSM, BATCH), 256, 0, stream>>>(Sb, LA, Hb);
    k_chunk3<<<dim3(NCH, NHEADSM, BATCH), 256, 0, stream>>>(XC, Hb, LA, Y);
    k_gated_rms<<<NROWS, 256, 0, stream>>>(Y, ZX, ws + W_RMSW + layer*1024);
    long woOff = (long)layer * DMODEL * DINNER;
    k_gemm_nt<<<dim3(8, 16), 256, 0, stream>>>(
        Y, d_in[9], woOff, (void*)Ob, NROWS, DMODEL, DINNER, (const float*)nullptr, flag, 0);
    k_add_ln<<<NROWS, 256, 0, stream>>>(X, Ob, ws + W_LNW + layer*512, ws + W_LNB + layer*512);
  }

  k_gemm_nt<<<dim3(16, 16), 256, 0, stream>>>(
      X, d_in[12], 0L, d_out, NROWS, 1000, DMODEL, ws + W_HEADB, flag, 1);
}

// Round 3
// 412.471 us; speedup vs baseline: 3.2554x; 1.8221x over previous
//
#include <hip/hip_runtime.h>

#define L_SEQ 512
#define BATCH 2
#define NROWS (BATCH*L_SEQ)   // 1024
#define DMODEL 512
#define DINNER 1024
#define DSTATE 128
#define NHEADSM 16
#define CONVD 1280
#define DINPROJ 2320
#define QCH 32
#define NCH 16
#define WI_PAD 2368           // 2320 padded to x64
#define WH_PAD 1024           // 1000 padded to x64

// ws float offsets (after 256B header holding the dtype flag)
#define W_CONVW 0
#define W_CONVB 10240
#define W_DTB   12800
#define W_ALOG  12832
#define W_DD    12864
#define W_RMSW  12896
#define W_LNW   14944
#define W_LNB   15968
#define W_HEADB 16992
#define O_X     18048
#define O_ZX    (O_X  + NROWS*DMODEL)    // 542336
#define O_XC    (O_ZX + NROWS*DINPROJ)   // 2918016
#define O_DT    (O_XC + NROWS*CONVD)     // 4228736
#define O_Y     (O_DT + NROWS*NHEADSM)   // 4245120
#define O_O     (O_Y  + NROWS*DINNER)    // 5293696
#define O_LA    (O_O  + NROWS*DMODEL)    // 5817984
#define O_S     (O_LA + 16384)           // 5834368  (also reused as H, in-place)
#define O_UB    (O_S  + 4194304)         // 10028672 -> bf16 region (ushort elems below)
// ushort offsets within bf16 region:
#define U_WI   0                          // 2 * 2368*512 = 2424832
#define U_WO   2424832                    // 2 * 512*1024 = 1048576
#define U_WH   3473408                    // 1024*512     = 524288
#define U_XBF  3997696                    // 1024*512
#define U_YBF  4521984                    // 1024*1024 -> end 5570560 ushorts
// total ws = 256 + 10028672*4 + 5570560*2 bytes ~ 51.3 MB

typedef __attribute__((ext_vector_type(8))) short short8;
typedef __attribute__((ext_vector_type(4))) float floatx4;

__device__ __forceinline__ float b2f(unsigned short h){ return __uint_as_float(((unsigned)h)<<16); }
__device__ __forceinline__ unsigned short f2b(float x){
  unsigned u = __float_as_uint(x);
  return (unsigned short)((u + 0x7fffu + ((u>>16)&1u)) >> 16);
}
__device__ __forceinline__ float loadIn(const void* p, long i, int f){
  return f ? b2f(((const unsigned short*)p)[i]) : ((const float*)p)[i];
}

// ---- dtype detect: low-16 of f32 words are a bf16 value iff data is packed bf16 ----
__global__ void k_detect(const unsigned* __restrict__ emb, int* __restrict__ flag){
  __shared__ int red[256];
  int t = threadIdx.x; int cnt = 0;
  for (int i = 0; i < 16; i++){
    unsigned w = emb[t*16 + i];
    unsigned e = (w >> 7) & 0xffu;
    cnt += (e >= 100 && e <= 126) ? 1 : 0;
  }
  red[t] = cnt; __syncthreads();
  if (t == 0){
    int s = 0;
    for (int i = 0; i < 256; i++) s += red[i];
    *flag = (s > 2048) ? 1 : 0;
  }
}

struct ConvArgs { const void* src[9]; int off[10]; };

__global__ void k_convert(ConvArgs a, const int* __restrict__ flag, float* __restrict__ dst){
  int f = *flag;
  int i = blockIdx.x*256 + threadIdx.x;
  if (i >= a.off[9]) return;
  int s = 0;
  while (i >= a.off[s+1]) s++;
  dst[i] = loadIn(a.src[s], i - a.off[s], f);
}

// weight -> padded bf16 copy (rows >= rowsSrc zeroed)
__global__ void k_prepw(const void* __restrict__ src, long srcOff, unsigned short* __restrict__ dst,
                        int rowsSrc, int K, const int* __restrict__ flag){
  int f = *flag;
  int r = blockIdx.x;
  long db = (long)r*K;
  if (r < rowsSrc){
    long sb = srcOff + db;
    for (int c = threadIdx.x; c < K; c += 256)
      dst[db + c] = f ? ((const unsigned short*)src)[sb + c] : f2b(((const float*)src)[sb + c]);
  } else {
    for (int c = threadIdx.x; c < K; c += 256) dst[db + c] = 0;
  }
}

__global__ void k_embed(const int* __restrict__ tok, const void* __restrict__ emb,
                        const int* __restrict__ flag, float* __restrict__ x,
                        unsigned short* __restrict__ xbf){
  int r = blockIdx.x; int f = *flag;
  long base = (long)tok[r] * DMODEL;
  for (int c = threadIdx.x; c < DMODEL; c += 256){
    float v = loadIn(emb, base + c, f);
    x[(long)r*DMODEL + c] = v;
    xbf[(long)r*DMODEL + c] = f ? ((const unsigned short*)emb)[base + c] : f2b(v);
  }
}

// ======== bf16 MFMA GEMM: C[M,N] = A[M,K] @ B[N,K]^T (+bias) ========
// 64x64 tile, 4 waves (2x2 of 2x2 16x16 frags), BK=64, XOR-swizzled LDS.
__global__ __launch_bounds__(256) void k_mfma_nt(
    const unsigned short* __restrict__ A, const unsigned short* __restrict__ B,
    void* __restrict__ C, int M, int N, int K,
    const float* __restrict__ bias, const int* __restrict__ flag, int outDual)
{
  __shared__ unsigned short As[4096];
  __shared__ unsigned short Bs[4096];
  int f = *flag;
  int t = threadIdx.x;
  int w = t >> 6, lane = t & 63;
  int quad = lane >> 4, l16 = lane & 15;
  int m0 = blockIdx.y << 6, n0 = blockIdx.x << 6;
  int wm = (w & 1) << 5, wn = (w >> 1) << 5;
  floatx4 acc[2][2];
  #pragma unroll
  for (int mi = 0; mi < 2; mi++)
    #pragma unroll
    for (int ni = 0; ni < 2; ni++) acc[mi][ni] = (floatx4){0.f,0.f,0.f,0.f};

  int idx0 = (w << 7) + lane;          // group ids [w*128, w*128+64)
  int r0s = idx0 >> 3, g0 = idx0 & 7;
  int idx1 = idx0 + 64;
  int r1s = idx1 >> 3, g1 = idx1 & 7;
  long aOff0 = (long)(m0 + r0s)*K + g0*8;
  long aOff1 = (long)(m0 + r1s)*K + g1*8;
  long bOff0 = (long)(n0 + r0s)*K + g0*8;
  long bOff1 = (long)(n0 + r1s)*K + g1*8;
  int w0 = r0s*64 + (g0 ^ (r0s & 7))*8;
  int w1 = r1s*64 + (g1 ^ (r1s & 7))*8;

  for (int k0 = 0; k0 < K; k0 += 64){
    short8 a0 = *(const short8*)&A[aOff0 + k0];
    short8 a1 = *(const short8*)&A[aOff1 + k0];
    short8 b0 = *(const short8*)&B[bOff0 + k0];
    short8 b1 = *(const short8*)&B[bOff1 + k0];
    __syncthreads();
    *(short8*)&As[w0] = a0; *(short8*)&As[w1] = a1;
    *(short8*)&Bs[w0] = b0; *(short8*)&Bs[w1] = b1;
    __syncthreads();
    #pragma unroll
    for (int ks = 0; ks < 2; ks++){
      short8 af[2], bfr[2];
      #pragma unroll
      for (int mi = 0; mi < 2; mi++){
        int r = wm + mi*16 + l16;
        int pos = ((ks << 2) + quad) ^ (r & 7);
        af[mi] = *(const short8*)&As[r*64 + pos*8];
      }
      #pragma unroll
      for (int ni = 0; ni < 2; ni++){
        int r = wn + ni*16 + l16;
        int pos = ((ks << 2) + quad) ^ (r & 7);
        bfr[ni] = *(const short8*)&Bs[r*64 + pos*8];
      }
      #pragma unroll
      for (int mi = 0; mi < 2; mi++)
        #pragma unroll
        for (int ni = 0; ni < 2; ni++)
          acc[mi][ni] = __builtin_amdgcn_mfma_f32_16x16x32_bf16(af[mi], bfr[ni], acc[mi][ni], 0, 0, 0);
    }
  }
  #pragma unroll
  for (int mi = 0; mi < 2; mi++)
    #pragma unroll
    for (int ni = 0; ni < 2; ni++){
      int col = n0 + wn + ni*16 + l16;
      if (col >= N) continue;
      float bv = bias ? bias[col] : 0.f;
      #pragma unroll
      for (int rr = 0; rr < 4; rr++){
        int row = m0 + wm + mi*16 + (quad << 2) + rr;
        float v = acc[mi][ni][rr] + bv;
        long idx = (long)row*N + col;
        if (outDual && f) ((unsigned short*)C)[idx] = f2b(v);
        else              ((float*)C)[idx] = v;
      }
    }
}

__global__ __launch_bounds__(256) void k_conv_dt(
    const float* __restrict__ zx, const float* __restrict__ cw, const float* __restrict__ cb,
    const float* __restrict__ dtb, float* __restrict__ xc, float* __restrict__ dt)
{
  int r = blockIdx.x; int b = r >> 9, l = r & 511;
  int t = threadIdx.x;
  for (int c = t; c < CONVD; c += 256){
    float s = cb[c];
    #pragma unroll
    for (int k = 0; k < 4; k++){
      int pos = l - 3 + k;
      if (pos >= 0)
        s = fmaf(zx[(long)(b*L_SEQ + pos)*DINPROJ + DINNER + c], cw[c*4 + k], s);
    }
    xc[(long)r*CONVD + c] = s / (1.f + __expf(-s));   // silu
  }
  if (t < NHEADSM){
    float v = zx[(long)r*DINPROJ + DINNER + CONVD + t] + dtb[t];
    dt[r*NHEADSM + t] = (v > 20.f) ? v : log1pf(__expf(v));  // softplus
  }
}

// ================= chunked SSD scan =================
__global__ __launch_bounds__(256) void k_chunk1(
    const float* __restrict__ xc, const float* __restrict__ dtbuf,
    const float* __restrict__ alog, const float* __restrict__ dvec,
    float* __restrict__ S, float* __restrict__ LAb, float* __restrict__ y)
{
  int c = blockIdx.x, h = blockIdx.y, b = blockIdx.z;
  int t = threadIdx.x;
  int l0 = c*QCH;
  __shared__ float Xs[QCH][68];
  __shared__ float Bs[QCH][132];
  __shared__ float Cs[QCH][132];
  __shared__ float Gs[QCH][33];
  __shared__ float dtl[QCH], lal[QCH], coef[QCH];
  float A  = -__expf(alog[h]);
  float Dv = dvec[h];
  if (t < QCH) dtl[t] = dtbuf[(b*L_SEQ + l0 + t)*NHEADSM + h];
  #pragma unroll
  for (int k = 0; k < 8; k++){
    int idx = t + k*256; int i = idx >> 6, p = idx & 63;
    Xs[i][p] = xc[(long)(b*L_SEQ + l0 + i)*CONVD + h*64 + p];
  }
  #pragma unroll
  for (int k = 0; k < 16; k++){
    int idx = t + k*256; int i = idx >> 7, n = idx & 127;
    long rb = (long)(b*L_SEQ + l0 + i)*CONVD;
    Bs[i][n] = xc[rb + DINNER + n];
    Cs[i][n] = xc[rb + DINNER + DSTATE + n];
  }
  __syncthreads();
  if (t == 0){
    float s = 0.f;
    for (int i = 0; i < QCH; i++){ s += dtl[i]; lal[i] = s*A; }
  }
  __syncthreads();
  if (t < QCH){
    coef[t] = __expf(lal[QCH-1] - lal[t]) * dtl[t];
    LAb[(b*NHEADSM + h)*L_SEQ + l0 + t] = lal[t];
  }
  __syncthreads();
  {
    int p = t >> 2, q = t & 3;
    float4 acc[8];
    #pragma unroll
    for (int k = 0; k < 8; k++) acc[k] = make_float4(0.f,0.f,0.f,0.f);
    for (int j = 0; j < QCH; j++){
      float xv = Xs[j][p] * coef[j];
      #pragma unroll
      for (int k = 0; k < 8; k++){
        float4 bv = *(const float4*)&Bs[j][q*4 + 16*k];
        acc[k].x = fmaf(xv, bv.x, acc[k].x);
        acc[k].y = fmaf(xv, bv.y, acc[k].y);
        acc[k].z = fmaf(xv, bv.z, acc[k].z);
        acc[k].w = fmaf(xv, bv.w, acc[k].w);
      }
    }
    long sb = ((long)((b*NHEADSM + h)*NCH + c))*8192 + p*128 + q*4;
    #pragma unroll
    for (int k = 0; k < 8; k++) *(float4*)&S[sb + 16*k] = acc[k];
  }
  {
    int i = t >> 3, jj = t & 7;
    float acc[4] = {};
    for (int nb = 0; nb < 32; nb++){
      float4 cv = *(const float4*)&Cs[i][nb*4];
      #pragma unroll
      for (int k = 0; k < 4; k++){
        float4 bv = *(const float4*)&Bs[jj + 8*k][nb*4];
        acc[k] += cv.x*bv.x + cv.y*bv.y + cv.z*bv.z + cv.w*bv.w;
      }
    }
    #pragma unroll
    for (int k = 0; k < 4; k++){
      int j = jj + 8*k;
      Gs[i][j] = (j <= i) ? __expf(lal[i] - lal[j]) * dtl[j] * acc[k] : 0.f;
    }
  }
  __syncthreads();
  {
    int i = t >> 3, p0 = (t & 7)*8;
    float4 a0 = *(const float4*)&Xs[i][p0];
    float4 a1 = *(const float4*)&Xs[i][p0+4];
    a0.x *= Dv; a0.y *= Dv; a0.z *= Dv; a0.w *= Dv;
    a1.x *= Dv; a1.y *= Dv; a1.z *= Dv; a1.w *= Dv;
    for (int j = 0; j < QCH; j++){
      float g = Gs[i][j];
      float4 x0 = *(const float4*)&Xs[j][p0];
      float4 x1 = *(const float4*)&Xs[j][p0+4];
      a0.x = fmaf(g, x0.x, a0.x); a0.y = fmaf(g, x0.y, a0.y);
      a0.z = fmaf(g, x0.z, a0.z); a0.w = fmaf(g, x0.w, a0.w);
      a1.x = fmaf(g, x1.x, a1.x); a1.y = fmaf(g, x1.y, a1.y);
      a1.z = fmaf(g, x1.z, a1.z); a1.w = fmaf(g, x1.w, a1.w);
    }
    long yb = (long)(b*L_SEQ + l0 + i)*DINNER + h*64 + p0;
    *(float4*)&y[yb]   = a0;
    *(float4*)&y[yb+4] = a1;
  }
}

// chunk2: serial state propagation, IN-PLACE: S[c] becomes H[c] (state before chunk c)
__global__ __launch_bounds__(256) void k_chunk2(
    float* __restrict__ S, const float* __restrict__ LAb)
{
  int h = blockIdx.x, b = blockIdx.y;
  int t = threadIdx.x;
  int p = t >> 2, n0 = (t & 3)*32;
  float4 hr[8];
  #pragma unroll
  for (int k = 0; k < 8; k++) hr[k] = make_float4(0.f,0.f,0.f,0.f);
  long base = ((long)((b*NHEADSM + h)*NCH))*8192 + p*128 + n0;
  int laBase = (b*NHEADSM + h)*L_SEQ;
  for (int c = 0; c < NCH; c++){
    long off = base + (long)c*8192;
    float4 sv[8];
    #pragma unroll
    for (int k = 0; k < 8; k++) sv[k] = *(const float4*)&S[off + 4*k];
    #pragma unroll
    for (int k = 0; k < 8; k++) *(float4*)&S[off + 4*k] = hr[k];
    float lam = __expf(LAb[laBase + c*QCH + QCH - 1]);
    #pragma unroll
    for (int k = 0; k < 8; k++){
      hr[k].x = fmaf(hr[k].x, lam, sv[k].x);
      hr[k].y = fmaf(hr[k].y, lam, sv[k].y);
      hr[k].z = fmaf(hr[k].z, lam, sv[k].z);
      hr[k].w = fmaf(hr[k].w, lam, sv[k].w);
    }
  }
}

// chunk3: Y += exp(la[i]) * (C_i . H_c[p,:])   (H lives in the S buffer)
__global__ __launch_bounds__(256) void k_chunk3(
    const float* __restrict__ xc, const float* __restrict__ H,
    const float* __restrict__ LAb, float* __restrict__ y)
{
  int c = blockIdx.x, h = blockIdx.y, b = blockIdx.z;
  int t = threadIdx.x, l0 = c*QCH;
  __shared__ float Cs[QCH][132];
  __shared__ float Hs[64][132];
  __shared__ float lal[QCH];
  if (t < QCH) lal[t] = LAb[(b*NHEADSM + h)*L_SEQ + l0 + t];
  #pragma unroll
  for (int k = 0; k < 16; k++){
    int idx = t + k*256; int i = idx >> 7, n = idx & 127;
    Cs[i][n] = xc[(long)(b*L_SEQ + l0 + i)*CONVD + DINNER + DSTATE + n];
  }
  long hb = ((long)((b*NHEADSM + h)*NCH + c))*8192;
  #pragma unroll
  for (int k = 0; k < 32; k++){
    int idx = t + k*256; int p = idx >> 7, n = idx & 127;
    Hs[p][n] = H[hb + idx];
  }
  __syncthreads();
  int i = t >> 3, p0 = (t & 7)*8;
  float acc[8] = {};
  for (int nb = 0; nb < 32; nb++){
    float4 cv = *(const float4*)&Cs[i][nb*4];
    #pragma unroll
    for (int q = 0; q < 8; q++){
      float4 hv = *(const float4*)&Hs[p0 + q][nb*4];
      acc[q] += cv.x*hv.x + cv.y*hv.y + cv.z*hv.z + cv.w*hv.w;
    }
  }
  float e = __expf(lal[i]);
  long yb = (long)(b*L_SEQ + l0 + i)*DINNER + h*64 + p0;
  #pragma unroll
  for (int q = 0; q < 8; q++)
    y[yb + q] = fmaf(e, acc[q], y[yb + q]);
}

__global__ __launch_bounds__(256) void k_gated_rms(
    const float* __restrict__ y, const float* __restrict__ zx, const float* __restrict__ rw,
    unsigned short* __restrict__ ybf)
{
  int r = blockIdx.x, t = threadIdx.x;
  float g[4]; float ss = 0.f;
  #pragma unroll
  for (int i = 0; i < 4; i++){
    int c = t + i*256;
    float z  = zx[(long)r*DINPROJ + c];
    float yv = y[(long)r*DINNER + c];
    float gz = z / (1.f + __expf(-z));
    g[i] = yv * gz;
    ss = fmaf(g[i], g[i], ss);
  }
  #pragma unroll
  for (int o = 1; o < 64; o <<= 1) ss += __shfl_xor(ss, o);
  __shared__ float red[4];
  int w = t >> 6, lane = t & 63;
  if (lane == 0) red[w] = ss;
  __syncthreads();
  float tot = red[0] + red[1] + red[2] + red[3];
  float sc = rsqrtf(tot / (float)DINNER + 1e-5f);
  #pragma unroll
  for (int i = 0; i < 4; i++){
    int c = t + i*256;
    ybf[(long)r*DINNER + c] = f2b(g[i] * sc * rw[c]);
  }
}

__global__ __launch_bounds__(256) void k_add_ln(
    float* __restrict__ x, const float* __restrict__ o,
    const float* __restrict__ lw, const float* __restrict__ lb,
    unsigned short* __restrict__ xbf)
{
  int r = blockIdx.x, t = threadIdx.x;
  float v[2]; float sm = 0.f;
  #pragma unroll
  for (int i = 0; i < 2; i++){ int c = t + i*256; v[i] = x[(long)r*DMODEL + c] + o[(long)r*DMODEL + c]; sm += v[i]; }
  #pragma unroll
  for (int off = 1; off < 64; off <<= 1) sm += __shfl_xor(sm, off);
  __shared__ float red[4]; __shared__ float red2[4];
  int w = t >> 6, lane = t & 63;
  if (lane == 0) red[w] = sm;
  __syncthreads();
  float mu = (red[0] + red[1] + red[2] + red[3]) / (float)DMODEL;
  float var = 0.f;
  #pragma unroll
  for (int i = 0; i < 2; i++){ v[i] -= mu; var = fmaf(v[i], v[i], var); }
  #pragma unroll
  for (int off = 1; off < 64; off <<= 1) var += __shfl_xor(var, off);
  if (lane == 0) red2[w] = var;
  __syncthreads();
  float vv = (red2[0] + red2[1] + red2[2] + red2[3]) / (float)DMODEL;
  float sc = rsqrtf(vv + 1e-5f);
  #pragma unroll
  for (int i = 0; i < 2; i++){
    int c = t + i*256;
    float ov = v[i]*sc*lw[c] + lb[c];
    x[(long)r*DMODEL + c] = ov;
    xbf[(long)r*DMODEL + c] = f2b(ov);
  }
}

extern "C" void kernel_launch(void* const* d_in, const int* in_sizes, int n_in,
                              void* d_out, int out_size, void* d_ws, size_t ws_size,
                              hipStream_t stream)
{
  const int* tokens = (const int*)d_in[0];
  const void* emb = d_in[1];
  int* flag = (int*)d_ws;
  float* ws = (float*)((char*)d_ws + 256);

  k_detect<<<1, 256, 0, stream>>>((const unsigned*)emb, flag);

  ConvArgs ca;
  const int sizes[9] = {10240, 2560, 32, 32, 32, 2048, 1024, 1024, 1000};
  const int idxs[9]  = {3, 4, 5, 6, 7, 8, 10, 11, 13};
  int off = 0;
  for (int s = 0; s < 9; s++){ ca.src[s] = d_in[idxs[s]]; ca.off[s] = off; off += sizes[s]; }
  ca.off[9] = off;
  k_convert<<<(off + 255)/256, 256, 0, stream>>>(ca, flag, ws);

  float* X  = ws + O_X;
  float* ZX = ws + O_ZX;
  float* XC = ws + O_XC;
  float* DT = ws + O_DT;
  float* Y  = ws + O_Y;
  float* Ob = ws + O_O;
  float* LA = ws + O_LA;
  float* Sb = ws + O_S;
  unsigned short* ub  = (unsigned short*)(ws + O_UB);
  unsigned short* WiB = ub + U_WI;
  unsigned short* WoB = ub + U_WO;
  unsigned short* WhB = ub + U_WH;
  unsigned short* Xbf = ub + U_XBF;
  unsigned short* Ybf = ub + U_YBF;

  // weight bf16 copies (padded rows)
  for (int layer = 0; layer < 2; layer++){
    k_prepw<<<WI_PAD, 256, 0, stream>>>(d_in[2], (long)layer*DINPROJ*DMODEL,
                                        WiB + (long)layer*WI_PAD*DMODEL, DINPROJ, DMODEL, flag);
    k_prepw<<<DMODEL, 256, 0, stream>>>(d_in[9], (long)layer*DMODEL*DINNER,
                                        WoB + (long)layer*DMODEL*DINNER, DMODEL, DINNER, flag);
  }
  k_prepw<<<WH_PAD, 256, 0, stream>>>(d_in[12], 0L, WhB, 1000, DMODEL, flag);

  k_embed<<<NROWS, 256, 0, stream>>>(tokens, emb, flag, X, Xbf);

  for (int layer = 0; layer < 2; layer++){
    k_mfma_nt<<<dim3(WI_PAD/64, NROWS/64), 256, 0, stream>>>(
        Xbf, WiB + (long)layer*WI_PAD*DMODEL, (void*)ZX,
        NROWS, DINPROJ, DMODEL, (const float*)nullptr, flag, 0);
    k_conv_dt<<<NROWS, 256, 0, stream>>>(
        ZX, ws + W_CONVW + layer*5120, ws + W_CONVB + layer*1280, ws + W_DTB + layer*16, XC, DT);
    k_chunk1<<<dim3(NCH, NHEADSM, BATCH), 256, 0, stream>>>(
        XC, DT, ws + W_ALOG + layer*16, ws + W_DD + layer*16, Sb, LA, Y);
    k_chunk2<<<dim3(NHEADSM, BATCH), 256, 0, stream>>>(Sb, LA);
    k_chunk3<<<dim3(NCH, NHEADSM, BATCH), 256, 0, stream>>>(XC, Sb, LA, Y);
    k_gated_rms<<<NROWS, 256, 0, stream>>>(Y, ZX, ws + W_RMSW + layer*1024, Ybf);
    k_mfma_nt<<<dim3(DMODEL/64, NROWS/64), 256, 0, stream>>>(
        Ybf, WoB + (long)layer*DMODEL*DINNER, (void*)Ob,
        NROWS, DMODEL, DINNER, (const float*)nullptr, flag, 0);
    k_add_ln<<<NROWS, 256, 0, stream>>>(X, Ob, ws + W_LNW + layer*512, ws + W_LNB + layer*512, Xbf);
  }

  k_mfma_nt<<<dim3(WH_PAD/64, NROWS/64), 256, 0, stream>>>(
      Xbf, WhB, d_out, NROWS, 1000, DMODEL, ws + W_HEADB, flag, 1);
}

// Round 4
// 322.895 us; speedup vs baseline: 4.1585x; 1.2774x over previous
//
#include <hip/hip_runtime.h>

#define L_SEQ 512
#define BATCH 2
#define NROWS (BATCH*L_SEQ)   // 1024
#define DMODEL 512
#define DINNER 1024
#define DSTATE 128
#define NHEADSM 16
#define CONVD 1280
#define DINPROJ 2320
#define QCH 32
#define NCH 16
#define WI_PAD 2368           // 2320 padded to x64
#define WH_PAD 1024           // 1000 padded to x64

// ws float offsets (after 256B header holding the dtype flag)
#define W_CONVW 0
#define W_CONVB 10240
#define W_DTB   12800
#define W_ALOG  12832
#define W_DD    12864
#define W_RMSW  12896
#define W_LNW   14944
#define W_LNB   15968
#define W_HEADB 16992
#define O_X     18048
#define O_ZX    (O_X  + NROWS*DMODEL)    // 542336
#define O_XC    (O_ZX + NROWS*DINPROJ)   // 2918016
#define O_DT    (O_XC + NROWS*CONVD)     // 4228736
#define O_Y     (O_DT + NROWS*NHEADSM)   // 4245120
#define O_O     (O_Y  + NROWS*DINNER)    // 5293696
#define O_LA    (O_O  + NROWS*DMODEL)    // 5817984
#define O_S     (O_LA + 16384)           // 5834368  (also reused as H, in-place)
#define O_UB    (O_S  + 4194304)         // 10028672 -> bf16 region (ushort elems below)
// ushort offsets within bf16 region:
#define U_WI   0                          // 2 * 2368*512 = 2424832
#define U_WO   2424832                    // 2 * 512*1024 = 1048576
#define U_WH   3473408                    // 1024*512     = 524288
#define U_XBF  3997696                    // 1024*512
#define U_YBF  4521984                    // 1024*1024 -> end 5570560 ushorts
// total ws = 256 + 10028672*4 + 5570560*2 bytes ~ 51.3 MB

typedef __attribute__((ext_vector_type(8))) short short8;
typedef __attribute__((ext_vector_type(4))) float floatx4;

__device__ __forceinline__ float b2f(unsigned short h){ return __uint_as_float(((unsigned)h)<<16); }
__device__ __forceinline__ unsigned short f2b(float x){
  unsigned u = __float_as_uint(x);
  return (unsigned short)((u + 0x7fffu + ((u>>16)&1u)) >> 16);
}
__device__ __forceinline__ float loadIn(const void* p, long i, int f){
  return f ? b2f(((const unsigned short*)p)[i]) : ((const float*)p)[i];
}

// ---- dtype detect: low-16 of f32 words are a bf16 value iff data is packed bf16 ----
__global__ void k_detect(const unsigned* __restrict__ emb, int* __restrict__ flag){
  __shared__ int red[256];
  int t = threadIdx.x; int cnt = 0;
  for (int i = 0; i < 16; i++){
    unsigned w = emb[t*16 + i];
    unsigned e = (w >> 7) & 0xffu;
    cnt += (e >= 100 && e <= 126) ? 1 : 0;
  }
  red[t] = cnt; __syncthreads();
  if (t == 0){
    int s = 0;
    for (int i = 0; i < 256; i++) s += red[i];
    *flag = (s > 2048) ? 1 : 0;
  }
}

struct ConvArgs { const void* src[9]; int off[10]; };

__global__ void k_convert(ConvArgs a, const int* __restrict__ flag, float* __restrict__ dst){
  int f = *flag;
  int i = blockIdx.x*256 + threadIdx.x;
  if (i >= a.off[9]) return;
  int s = 0;
  while (i >= a.off[s+1]) s++;
  dst[i] = loadIn(a.src[s], i - a.off[s], f);
}

// all weights -> padded bf16 copies, one kernel (segments by blockIdx)
__global__ void k_prepall(const void* __restrict__ wi, const void* __restrict__ wo,
                          const void* __restrict__ wh,
                          unsigned short* __restrict__ WiB, unsigned short* __restrict__ WoB,
                          unsigned short* __restrict__ WhB, const int* __restrict__ flag)
{
  int f = *flag;
  int r = blockIdx.x;
  const void* src = nullptr; unsigned short* dst; long sb = 0, db; int K; bool zero = false;
  if (r < 2*WI_PAD){
    int layer = r / WI_PAD, row = r % WI_PAD;
    K = DMODEL; dst = WiB; db = ((long)layer*WI_PAD + row)*DMODEL;
    if (row < DINPROJ){ src = wi; sb = ((long)layer*DINPROJ + row)*DMODEL; } else zero = true;
  } else if (r < 2*WI_PAD + 2*DMODEL){
    int rr = r - 2*WI_PAD;
    K = DINNER; dst = WoB; db = (long)rr*DINNER;
    src = wo; sb = db;
  } else {
    int row = r - 2*WI_PAD - 2*DMODEL;
    K = DMODEL; dst = WhB; db = (long)row*DMODEL;
    if (row < 1000){ src = wh; sb = db; } else zero = true;
  }
  for (int c = threadIdx.x; c < K; c += 256)
    dst[db + c] = zero ? (unsigned short)0
                       : (f ? ((const unsigned short*)src)[sb + c] : f2b(((const float*)src)[sb + c]));
}

__global__ void k_embed(const int* __restrict__ tok, const void* __restrict__ emb,
                        const int* __restrict__ flag, float* __restrict__ x,
                        unsigned short* __restrict__ xbf){
  int r = blockIdx.x; int f = *flag;
  long base = (long)tok[r] * DMODEL;
  for (int c = threadIdx.x; c < DMODEL; c += 256){
    float v = loadIn(emb, base + c, f);
    x[(long)r*DMODEL + c] = v;
    xbf[(long)r*DMODEL + c] = f ? ((const unsigned short*)emb)[base + c] : f2b(v);
  }
}

// ======== bf16 MFMA GEMM: C[M,N] = A[M,K] @ B[N,K]^T (+bias) ========
__global__ __launch_bounds__(256) void k_mfma_nt(
    const unsigned short* __restrict__ A, const unsigned short* __restrict__ B,
    void* __restrict__ C, int M, int N, int K,
    const float* __restrict__ bias, const int* __restrict__ flag, int outDual)
{
  __shared__ unsigned short As[4096];
  __shared__ unsigned short Bs[4096];
  int f = *flag;
  int t = threadIdx.x;
  int w = t >> 6, lane = t & 63;
  int quad = lane >> 4, l16 = lane & 15;
  int m0 = blockIdx.y << 6, n0 = blockIdx.x << 6;
  int wm = (w & 1) << 5, wn = (w >> 1) << 5;
  floatx4 acc[2][2];
  #pragma unroll
  for (int mi = 0; mi < 2; mi++)
    #pragma unroll
    for (int ni = 0; ni < 2; ni++) acc[mi][ni] = (floatx4){0.f,0.f,0.f,0.f};

  int idx0 = (w << 7) + lane;
  int r0s = idx0 >> 3, g0 = idx0 & 7;
  int idx1 = idx0 + 64;
  int r1s = idx1 >> 3, g1 = idx1 & 7;
  long aOff0 = (long)(m0 + r0s)*K + g0*8;
  long aOff1 = (long)(m0 + r1s)*K + g1*8;
  long bOff0 = (long)(n0 + r0s)*K + g0*8;
  long bOff1 = (long)(n0 + r1s)*K + g1*8;
  int w0 = r0s*64 + (g0 ^ (r0s & 7))*8;
  int w1 = r1s*64 + (g1 ^ (r1s & 7))*8;

  for (int k0 = 0; k0 < K; k0 += 64){
    short8 a0 = *(const short8*)&A[aOff0 + k0];
    short8 a1 = *(const short8*)&A[aOff1 + k0];
    short8 b0 = *(const short8*)&B[bOff0 + k0];
    short8 b1 = *(const short8*)&B[bOff1 + k0];
    __syncthreads();
    *(short8*)&As[w0] = a0; *(short8*)&As[w1] = a1;
    *(short8*)&Bs[w0] = b0; *(short8*)&Bs[w1] = b1;
    __syncthreads();
    #pragma unroll
    for (int ks = 0; ks < 2; ks++){
      short8 af[2], bfr[2];
      #pragma unroll
      for (int mi = 0; mi < 2; mi++){
        int r = wm + mi*16 + l16;
        int pos = ((ks << 2) + quad) ^ (r & 7);
        af[mi] = *(const short8*)&As[r*64 + pos*8];
      }
      #pragma unroll
      for (int ni = 0; ni < 2; ni++){
        int r = wn + ni*16 + l16;
        int pos = ((ks << 2) + quad) ^ (r & 7);
        bfr[ni] = *(const short8*)&Bs[r*64 + pos*8];
      }
      #pragma unroll
      for (int mi = 0; mi < 2; mi++)
        #pragma unroll
        for (int ni = 0; ni < 2; ni++)
          acc[mi][ni] = __builtin_amdgcn_mfma_f32_16x16x32_bf16(af[mi], bfr[ni], acc[mi][ni], 0, 0, 0);
    }
  }
  #pragma unroll
  for (int mi = 0; mi < 2; mi++)
    #pragma unroll
    for (int ni = 0; ni < 2; ni++){
      int col = n0 + wn + ni*16 + l16;
      if (col >= N) continue;
      float bv = bias ? bias[col] : 0.f;
      #pragma unroll
      for (int rr = 0; rr < 4; rr++){
        int row = m0 + wm + mi*16 + (quad << 2) + rr;
        float v = acc[mi][ni][rr] + bv;
        long idx = (long)row*N + col;
        if (outDual && f) ((unsigned short*)C)[idx] = f2b(v);
        else              ((float*)C)[idx] = v;
      }
    }
}

__global__ __launch_bounds__(256) void k_conv_dt(
    const float* __restrict__ zx, const float* __restrict__ cw, const float* __restrict__ cb,
    const float* __restrict__ dtb, float* __restrict__ xc, float* __restrict__ dt)
{
  int r = blockIdx.x; int b = r >> 9, l = r & 511;
  int t = threadIdx.x;
  for (int c = t; c < CONVD; c += 256){
    float s = cb[c];
    #pragma unroll
    for (int k = 0; k < 4; k++){
      int pos = l - 3 + k;
      if (pos >= 0)
        s = fmaf(zx[(long)(b*L_SEQ + pos)*DINPROJ + DINNER + c], cw[c*4 + k], s);
    }
    xc[(long)r*CONVD + c] = s / (1.f + __expf(-s));   // silu
  }
  if (t < NHEADSM){
    float v = zx[(long)r*DINPROJ + DINNER + CONVD + t] + dtb[t];
    dt[r*NHEADSM + t] = (v > 20.f) ? v : log1pf(__expf(v));  // softplus
  }
}

// ================= chunked SSD scan =================
__global__ __launch_bounds__(256) void k_chunk1(
    const float* __restrict__ xc, const float* __restrict__ dtbuf,
    const float* __restrict__ alog, const float* __restrict__ dvec,
    float* __restrict__ S, float* __restrict__ LAb, float* __restrict__ y)
{
  int c = blockIdx.x, h = blockIdx.y, b = blockIdx.z;
  int t = threadIdx.x;
  int l0 = c*QCH;
  __shared__ float Xs[QCH][68];
  __shared__ float Bs[QCH][132];
  __shared__ float Cs[QCH][132];
  __shared__ float Gs[QCH][33];
  __shared__ float dtl[QCH], lal[QCH], coef[QCH];
  float A  = -__expf(alog[h]);
  float Dv = dvec[h];
  if (t < QCH) dtl[t] = dtbuf[(b*L_SEQ + l0 + t)*NHEADSM + h];
  #pragma unroll
  for (int k = 0; k < 8; k++){
    int idx = t + k*256; int i = idx >> 6, p = idx & 63;
    Xs[i][p] = xc[(long)(b*L_SEQ + l0 + i)*CONVD + h*64 + p];
  }
  #pragma unroll
  for (int k = 0; k < 16; k++){
    int idx = t + k*256; int i = idx >> 7, n = idx & 127;
    long rb = (long)(b*L_SEQ + l0 + i)*CONVD;
    Bs[i][n] = xc[rb + DINNER + n];
    Cs[i][n] = xc[rb + DINNER + DSTATE + n];
  }
  __syncthreads();
  if (t == 0){
    float s = 0.f;
    for (int i = 0; i < QCH; i++){ s += dtl[i]; lal[i] = s*A; }
  }
  __syncthreads();
  if (t < QCH){
    coef[t] = __expf(lal[QCH-1] - lal[t]) * dtl[t];
    LAb[(b*NHEADSM + h)*L_SEQ + l0 + t] = lal[t];
  }
  __syncthreads();
  {
    int p = t >> 2, q = t & 3;
    float4 acc[8];
    #pragma unroll
    for (int k = 0; k < 8; k++) acc[k] = make_float4(0.f,0.f,0.f,0.f);
    for (int j = 0; j < QCH; j++){
      float xv = Xs[j][p] * coef[j];
      #pragma unroll
      for (int k = 0; k < 8; k++){
        float4 bv = *(const float4*)&Bs[j][q*4 + 16*k];
        acc[k].x = fmaf(xv, bv.x, acc[k].x);
        acc[k].y = fmaf(xv, bv.y, acc[k].y);
        acc[k].z = fmaf(xv, bv.z, acc[k].z);
        acc[k].w = fmaf(xv, bv.w, acc[k].w);
      }
    }
    long sb = ((long)((b*NHEADSM + h)*NCH + c))*8192 + p*128 + q*4;
    #pragma unroll
    for (int k = 0; k < 8; k++) *(float4*)&S[sb + 16*k] = acc[k];
  }
  {
    int i = t >> 3, jj = t & 7;
    float acc[4] = {};
    for (int nb = 0; nb < 32; nb++){
      float4 cv = *(const float4*)&Cs[i][nb*4];
      #pragma unroll
      for (int k = 0; k < 4; k++){
        float4 bv = *(const float4*)&Bs[jj + 8*k][nb*4];
        acc[k] += cv.x*bv.x + cv.y*bv.y + cv.z*bv.z + cv.w*bv.w;
      }
    }
    #pragma unroll
    for (int k = 0; k < 4; k++){
      int j = jj + 8*k;
      Gs[i][j] = (j <= i) ? __expf(lal[i] - lal[j]) * dtl[j] * acc[k] : 0.f;
    }
  }
  __syncthreads();
  {
    int i = t >> 3, p0 = (t & 7)*8;
    float4 a0 = *(const float4*)&Xs[i][p0];
    float4 a1 = *(const float4*)&Xs[i][p0+4];
    a0.x *= Dv; a0.y *= Dv; a0.z *= Dv; a0.w *= Dv;
    a1.x *= Dv; a1.y *= Dv; a1.z *= Dv; a1.w *= Dv;
    for (int j = 0; j < QCH; j++){
      float g = Gs[i][j];
      float4 x0 = *(const float4*)&Xs[j][p0];
      float4 x1 = *(const float4*)&Xs[j][p0+4];
      a0.x = fmaf(g, x0.x, a0.x); a0.y = fmaf(g, x0.y, a0.y);
      a0.z = fmaf(g, x0.z, a0.z); a0.w = fmaf(g, x0.w, a0.w);
      a1.x = fmaf(g, x1.x, a1.x); a1.y = fmaf(g, x1.y, a1.y);
      a1.z = fmaf(g, x1.z, a1.z); a1.w = fmaf(g, x1.w, a1.w);
    }
    long yb = (long)(b*L_SEQ + l0 + i)*DINNER + h*64 + p0;
    *(float4*)&y[yb]   = a0;
    *(float4*)&y[yb+4] = a1;
  }
}

// chunk2: state propagation, IN-PLACE, one thread per state element.
// grid: 1024 blocks (32 per (b,h)); each thread owns one (p,n) chain over 16 chunks.
__global__ __launch_bounds__(256) void k_chunk2(
    float* __restrict__ S, const float* __restrict__ LAb)
{
  int bh = blockIdx.x >> 5;
  int e = ((blockIdx.x & 31) << 8) + threadIdx.x;     // 0..8191
  long base = (long)bh*NCH*8192 + e;
  int laBase = bh*L_SEQ;
  float lam[NCH];
  #pragma unroll
  for (int c = 0; c < NCH; c++) lam[c] = __expf(LAb[laBase + c*QCH + QCH - 1]);
  float hr = 0.f;
  #pragma unroll
  for (int c = 0; c < NCH; c++){
    long off = base + (long)c*8192;
    float sv = S[off];
    S[off] = hr;
    hr = fmaf(hr, lam[c], sv);
  }
}

// chunk3: Y += exp(la[i]) * (C_i . H_c[p,:])   (H lives in the S buffer)
__global__ __launch_bounds__(256) void k_chunk3(
    const float* __restrict__ xc, const float* __restrict__ H,
    const float* __restrict__ LAb, float* __restrict__ y)
{
  int c = blockIdx.x, h = blockIdx.y, b = blockIdx.z;
  int t = threadIdx.x, l0 = c*QCH;
  __shared__ float Cs[QCH][132];
  __shared__ float Hs[64][132];
  __shared__ float lal[QCH];
  if (t < QCH) lal[t] = LAb[(b*NHEADSM + h)*L_SEQ + l0 + t];
  #pragma unroll
  for (int k = 0; k < 16; k++){
    int idx = t + k*256; int i = idx >> 7, n = idx & 127;
    Cs[i][n] = xc[(long)(b*L_SEQ + l0 + i)*CONVD + DINNER + DSTATE + n];
  }
  long hb = ((long)((b*NHEADSM + h)*NCH + c))*8192;
  #pragma unroll
  for (int k = 0; k < 32; k++){
    int idx = t + k*256; int p = idx >> 7, n = idx & 127;
    Hs[p][n] = H[hb + idx];
  }
  __syncthreads();
  int i = t >> 3, p0 = (t & 7)*8;
  float acc[8] = {};
  for (int nb = 0; nb < 32; nb++){
    float4 cv = *(const float4*)&Cs[i][nb*4];
    #pragma unroll
    for (int q = 0; q < 8; q++){
      float4 hv = *(const float4*)&Hs[p0 + q][nb*4];
      acc[q] += cv.x*hv.x + cv.y*hv.y + cv.z*hv.z + cv.w*hv.w;
    }
  }
  float e = __expf(lal[i]);
  long yb = (long)(b*L_SEQ + l0 + i)*DINNER + h*64 + p0;
  #pragma unroll
  for (int q = 0; q < 8; q++)
    y[yb + q] = fmaf(e, acc[q], y[yb + q]);
}

__global__ __launch_bounds__(256) void k_gated_rms(
    const float* __restrict__ y, const float* __restrict__ zx, const float* __restrict__ rw,
    unsigned short* __restrict__ ybf)
{
  int r = blockIdx.x, t = threadIdx.x;
  float g[4]; float ss = 0.f;
  #pragma unroll
  for (int i = 0; i < 4; i++){
    int c = t + i*256;
    float z  = zx[(long)r*DINPROJ + c];
    float yv = y[(long)r*DINNER + c];
    float gz = z / (1.f + __expf(-z));
    g[i] = yv * gz;
    ss = fmaf(g[i], g[i], ss);
  }
  #pragma unroll
  for (int o = 1; o < 64; o <<= 1) ss += __shfl_xor(ss, o);
  __shared__ float red[4];
  int w = t >> 6, lane = t & 63;
  if (lane == 0) red[w] = ss;
  __syncthreads();
  float tot = red[0] + red[1] + red[2] + red[3];
  float sc = rsqrtf(tot / (float)DINNER + 1e-5f);
  #pragma unroll
  for (int i = 0; i < 4; i++){
    int c = t + i*256;
    ybf[(long)r*DINNER + c] = f2b(g[i] * sc * rw[c]);
  }
}

__global__ __launch_bounds__(256) void k_add_ln(
    float* __restrict__ x, const float* __restrict__ o,
    const float* __restrict__ lw, const float* __restrict__ lb,
    unsigned short* __restrict__ xbf)
{
  int r = blockIdx.x, t = threadIdx.x;
  float v[2]; float sm = 0.f;
  #pragma unroll
  for (int i = 0; i < 2; i++){ int c = t + i*256; v[i] = x[(long)r*DMODEL + c] + o[(long)r*DMODEL + c]; sm += v[i]; }
  #pragma unroll
  for (int off = 1; off < 64; off <<= 1) sm += __shfl_xor(sm, off);
  __shared__ float red[4]; __shared__ float red2[4];
  int w = t >> 6, lane = t & 63;
  if (lane == 0) red[w] = sm;
  __syncthreads();
  float mu = (red[0] + red[1] + red[2] + red[3]) / (float)DMODEL;
  float var = 0.f;
  #pragma unroll
  for (int i = 0; i < 2; i++){ v[i] -= mu; var = fmaf(v[i], v[i], var); }
  #pragma unroll
  for (int off = 1; off < 64; off <<= 1) var += __shfl_xor(var, off);
  if (lane == 0) red2[w] = var;
  __syncthreads();
  float vv = (red2[0] + red2[1] + red2[2] + red2[3]) / (float)DMODEL;
  float sc = rsqrtf(vv + 1e-5f);
  #pragma unroll
  for (int i = 0; i < 2; i++){
    int c = t + i*256;
    float ov = v[i]*sc*lw[c] + lb[c];
    x[(long)r*DMODEL + c] = ov;
    xbf[(long)r*DMODEL + c] = f2b(ov);
  }
}

extern "C" void kernel_launch(void* const* d_in, const int* in_sizes, int n_in,
                              void* d_out, int out_size, void* d_ws, size_t ws_size,
                              hipStream_t stream)
{
  const int* tokens = (const int*)d_in[0];
  const void* emb = d_in[1];
  int* flag = (int*)d_ws;
  float* ws = (float*)((char*)d_ws + 256);

  k_detect<<<1, 256, 0, stream>>>((const unsigned*)emb, flag);

  ConvArgs ca;
  const int sizes[9] = {10240, 2560, 32, 32, 32, 2048, 1024, 1024, 1000};
  const int idxs[9]  = {3, 4, 5, 6, 7, 8, 10, 11, 13};
  int off = 0;
  for (int s = 0; s < 9; s++){ ca.src[s] = d_in[idxs[s]]; ca.off[s] = off; off += sizes[s]; }
  ca.off[9] = off;
  k_convert<<<(off + 255)/256, 256, 0, stream>>>(ca, flag, ws);

  float* X  = ws + O_X;
  float* ZX = ws + O_ZX;
  float* XC = ws + O_XC;
  float* DT = ws + O_DT;
  float* Y  = ws + O_Y;
  float* Ob = ws + O_O;
  float* LA = ws + O_LA;
  float* Sb = ws + O_S;
  unsigned short* ub  = (unsigned short*)(ws + O_UB);
  unsigned short* WiB = ub + U_WI;
  unsigned short* WoB = ub + U_WO;
  unsigned short* WhB = ub + U_WH;
  unsigned short* Xbf = ub + U_XBF;
  unsigned short* Ybf = ub + U_YBF;

  k_prepall<<<2*WI_PAD + 2*DMODEL + WH_PAD, 256, 0, stream>>>(
      d_in[2], d_in[9], d_in[12], WiB, WoB, WhB, flag);

  k_embed<<<NROWS, 256, 0, stream>>>(tokens, emb, flag, X, Xbf);

  for (int layer = 0; layer < 2; layer++){
    k_mfma_nt<<<dim3(WI_PAD/64, NROWS/64), 256, 0, stream>>>(
        Xbf, WiB + (long)layer*WI_PAD*DMODEL, (void*)ZX,
        NROWS, DINPROJ, DMODEL, (const float*)nullptr, flag, 0);
    k_conv_dt<<<NROWS, 256, 0, stream>>>(
        ZX, ws + W_CONVW + layer*5120, ws + W_CONVB + layer*1280, ws + W_DTB + layer*16, XC, DT);
    k_chunk1<<<dim3(NCH, NHEADSM, BATCH), 256, 0, stream>>>(
        XC, DT, ws + W_ALOG + layer*16, ws + W_DD + layer*16, Sb, LA, Y);
    k_chunk2<<<1024, 256, 0, stream>>>(Sb, LA);
    k_chunk3<<<dim3(NCH, NHEADSM, BATCH), 256, 0, stream>>>(XC, Sb, LA, Y);
    k_gated_rms<<<NROWS, 256, 0, stream>>>(Y, ZX, ws + W_RMSW + layer*1024, Ybf);
    k_mfma_nt<<<dim3(DMODEL/64, NROWS/64), 256, 0, stream>>>(
        Ybf, WoB + (long)layer*DMODEL*DINNER, (void*)Ob,
        NROWS, DMODEL, DINNER, (const float*)nullptr, flag, 0);
    k_add_ln<<<NROWS, 256, 0, stream>>>(X, Ob, ws + W_LNW + layer*512, ws + W_LNB + layer*512, Xbf);
  }

  k_mfma_nt<<<dim3(WH_PAD/64, NROWS/64), 256, 0, stream>>>(
      Xbf, WhB, d_out, NROWS, 1000, DMODEL, ws + W_HEADB, flag, 1);
}

// Round 5
// 255.814 us; speedup vs baseline: 5.2489x; 1.2622x over previous
//
#include <hip/hip_runtime.h>

#define L_SEQ 512
#define BATCH 2
#define NROWS (BATCH*L_SEQ)   // 1024
#define DMODEL 512
#define DINNER 1024
#define DSTATE 128
#define NHEADSM 16
#define CONVD 1280
#define DINPROJ 2320
#define QCH 32
#define NCH 16
#define WI_PAD 2368           // 2320 padded to x64
#define WH_PAD 1024           // 1000 padded to x64

// ws float offsets (after 256B header holding the dtype flag)
#define W_CONVW 0
#define W_CONVB 10240
#define W_DTB   12800
#define W_ALOG  12832
#define W_DD    12864
#define W_RMSW  12896
#define W_LNW   14944
#define W_LNB   15968
#define W_HEADB 16992
#define O_X     18048
#define O_ZX    (O_X  + NROWS*DMODEL)
#define O_XC    (O_ZX + NROWS*DINPROJ)
#define O_DT    (O_XC + NROWS*CONVD)
#define O_Y     (O_DT + NROWS*NHEADSM)
#define O_O     (O_Y  + NROWS*DINNER)
#define O_LA    (O_O  + NROWS*DMODEL)
#define O_S     (O_LA + 16384)
#define O_UB    (O_S  + 4194304)
// ushort offsets within bf16 region:
#define U_WI   0
#define U_WO   2424832
#define U_WH   3473408
#define U_XBF  3997696
#define U_YBF  4521984

#define NSMALL 17992          // total small-param floats
#define NPREPW (2*WI_PAD + 2*DMODEL + WH_PAD)   // 6848 weight rows

typedef __attribute__((ext_vector_type(8))) short short8;
typedef __attribute__((ext_vector_type(4))) float floatx4;

__device__ __forceinline__ float b2f(unsigned short h){ return __uint_as_float(((unsigned)h)<<16); }
__device__ __forceinline__ unsigned short f2b(float x){
  unsigned u = __float_as_uint(x);
  return (unsigned short)((u + 0x7fffu + ((u>>16)&1u)) >> 16);
}
__device__ __forceinline__ float loadIn(const void* p, long i, int f){
  return f ? b2f(((const unsigned short*)p)[i]) : ((const float*)p)[i];
}

// ---- dtype detect: low-16 of f32 words are a bf16 value iff data is packed bf16 ----
__global__ void k_detect(const unsigned* __restrict__ emb, int* __restrict__ flag){
  __shared__ int red[256];
  int t = threadIdx.x; int cnt = 0;
  for (int i = 0; i < 16; i++){
    unsigned w = emb[t*16 + i];
    unsigned e = (w >> 7) & 0xffu;
    cnt += (e >= 100 && e <= 126) ? 1 : 0;
  }
  red[t] = cnt; __syncthreads();
  if (t == 0){
    int s = 0;
    for (int i = 0; i < 256; i++) s += red[i];
    *flag = (s > 2048) ? 1 : 0;
  }
}

struct ConvArgs { const void* src[9]; int off[10]; };

// fused startup: small-param convert + weight bf16 prep + embedding
__global__ void k_prep(ConvArgs a, const void* __restrict__ wi, const void* __restrict__ wo,
                       const void* __restrict__ wh, const int* __restrict__ tok,
                       const void* __restrict__ emb, const int* __restrict__ flag,
                       float* __restrict__ dstSmall,
                       unsigned short* __restrict__ WiB, unsigned short* __restrict__ WoB,
                       unsigned short* __restrict__ WhB,
                       float* __restrict__ x, unsigned short* __restrict__ xbf)
{
  int f = *flag;
  int blk = blockIdx.x;
  if (blk < 71){
    int i = blk*256 + threadIdx.x;
    if (i < a.off[9]){
      int s = 0;
      while (i >= a.off[s+1]) s++;
      dstSmall[i] = loadIn(a.src[s], i - a.off[s], f);
    }
    return;
  }
  blk -= 71;
  if (blk < NPREPW){
    int r = blk;
    const void* src = nullptr; unsigned short* dst; long sb = 0, db; int K; bool zero = false;
    if (r < 2*WI_PAD){
      int layer = r / WI_PAD, row = r % WI_PAD;
      K = DMODEL; dst = WiB; db = ((long)layer*WI_PAD + row)*DMODEL;
      if (row < DINPROJ){ src = wi; sb = ((long)layer*DINPROJ + row)*DMODEL; } else zero = true;
    } else if (r < 2*WI_PAD + 2*DMODEL){
      int rr = r - 2*WI_PAD;
      K = DINNER; dst = WoB; db = (long)rr*DINNER;
      src = wo; sb = db;
    } else {
      int row = r - 2*WI_PAD - 2*DMODEL;
      K = DMODEL; dst = WhB; db = (long)row*DMODEL;
      if (row < 1000){ src = wh; sb = db; } else zero = true;
    }
    for (int c = threadIdx.x; c < K; c += 256)
      dst[db + c] = zero ? (unsigned short)0
                         : (f ? ((const unsigned short*)src)[sb + c] : f2b(((const float*)src)[sb + c]));
    return;
  }
  int r = blk - NPREPW;   // embed row
  long base = (long)tok[r] * DMODEL;
  for (int c = threadIdx.x; c < DMODEL; c += 256){
    float v = loadIn(emb, base + c, f);
    x[(long)r*DMODEL + c] = v;
    xbf[(long)r*DMODEL + c] = f ? ((const unsigned short*)emb)[base + c] : f2b(v);
  }
}

// ======== bf16 MFMA GEMM: C[M,N] = A[M,K] @ B[N,K]^T (+bias) ========
__global__ __launch_bounds__(256) void k_mfma_nt(
    const unsigned short* __restrict__ A, const unsigned short* __restrict__ B,
    void* __restrict__ C, int M, int N, int K,
    const float* __restrict__ bias, const int* __restrict__ flag, int outDual)
{
  __shared__ unsigned short As[4096];
  __shared__ unsigned short Bs[4096];
  int f = *flag;
  int t = threadIdx.x;
  int w = t >> 6, lane = t & 63;
  int quad = lane >> 4, l16 = lane & 15;
  int m0 = blockIdx.y << 6, n0 = blockIdx.x << 6;
  int wm = (w & 1) << 5, wn = (w >> 1) << 5;
  floatx4 acc[2][2];
  #pragma unroll
  for (int mi = 0; mi < 2; mi++)
    #pragma unroll
    for (int ni = 0; ni < 2; ni++) acc[mi][ni] = (floatx4){0.f,0.f,0.f,0.f};

  int idx0 = (w << 7) + lane;
  int r0s = idx0 >> 3, g0 = idx0 & 7;
  int idx1 = idx0 + 64;
  int r1s = idx1 >> 3, g1 = idx1 & 7;
  long aOff0 = (long)(m0 + r0s)*K + g0*8;
  long aOff1 = (long)(m0 + r1s)*K + g1*8;
  long bOff0 = (long)(n0 + r0s)*K + g0*8;
  long bOff1 = (long)(n0 + r1s)*K + g1*8;
  int w0 = r0s*64 + (g0 ^ (r0s & 7))*8;
  int w1 = r1s*64 + (g1 ^ (r1s & 7))*8;

  for (int k0 = 0; k0 < K; k0 += 64){
    short8 a0 = *(const short8*)&A[aOff0 + k0];
    short8 a1 = *(const short8*)&A[aOff1 + k0];
    short8 b0 = *(const short8*)&B[bOff0 + k0];
    short8 b1 = *(const short8*)&B[bOff1 + k0];
    __syncthreads();
    *(short8*)&As[w0] = a0; *(short8*)&As[w1] = a1;
    *(short8*)&Bs[w0] = b0; *(short8*)&Bs[w1] = b1;
    __syncthreads();
    #pragma unroll
    for (int ks = 0; ks < 2; ks++){
      short8 af[2], bfr[2];
      #pragma unroll
      for (int mi = 0; mi < 2; mi++){
        int r = wm + mi*16 + l16;
        int pos = ((ks << 2) + quad) ^ (r & 7);
        af[mi] = *(const short8*)&As[r*64 + pos*8];
      }
      #pragma unroll
      for (int ni = 0; ni < 2; ni++){
        int r = wn + ni*16 + l16;
        int pos = ((ks << 2) + quad) ^ (r & 7);
        bfr[ni] = *(const short8*)&Bs[r*64 + pos*8];
      }
      #pragma unroll
      for (int mi = 0; mi < 2; mi++)
        #pragma unroll
        for (int ni = 0; ni < 2; ni++)
          acc[mi][ni] = __builtin_amdgcn_mfma_f32_16x16x32_bf16(af[mi], bfr[ni], acc[mi][ni], 0, 0, 0);
    }
  }
  #pragma unroll
  for (int mi = 0; mi < 2; mi++)
    #pragma unroll
    for (int ni = 0; ni < 2; ni++){
      int col = n0 + wn + ni*16 + l16;
      if (col >= N) continue;
      float bv = bias ? bias[col] : 0.f;
      #pragma unroll
      for (int rr = 0; rr < 4; rr++){
        int row = m0 + wm + mi*16 + (quad << 2) + rr;
        float v = acc[mi][ni][rr] + bv;
        long idx = (long)row*N + col;
        if (outDual && f) ((unsigned short*)C)[idx] = f2b(v);
        else              ((float*)C)[idx] = v;
      }
    }
}

__global__ __launch_bounds__(256) void k_conv_dt(
    const float* __restrict__ zx, const float* __restrict__ cw, const float* __restrict__ cb,
    const float* __restrict__ dtb, float* __restrict__ xc, float* __restrict__ dt)
{
  int r = blockIdx.x; int b = r >> 9, l = r & 511;
  int t = threadIdx.x;
  for (int c = t; c < CONVD; c += 256){
    float s = cb[c];
    #pragma unroll
    for (int k = 0; k < 4; k++){
      int pos = l - 3 + k;
      if (pos >= 0)
        s = fmaf(zx[(long)(b*L_SEQ + pos)*DINPROJ + DINNER + c], cw[c*4 + k], s);
    }
    xc[(long)r*CONVD + c] = s / (1.f + __expf(-s));   // silu
  }
  if (t < NHEADSM){
    float v = zx[(long)r*DINPROJ + DINNER + CONVD + t] + dtb[t];
    dt[r*NHEADSM + t] = (v > 20.f) ? v : log1pf(__expf(v));  // softplus
  }
}

// ================= chunked SSD scan (MFMA) =================
// chunk1 per (c,h,b): S = (coef.X)^T B  [64x128,K=32], G = C.B^T [32x32,K=128],
// Y = G.X + D*x [32x64,K=32]. All via NT mfma primitive (both operands [out][K]).
__global__ __launch_bounds__(256) void k_chunk1(
    const float* __restrict__ xc, const float* __restrict__ dtbuf,
    const float* __restrict__ alog, const float* __restrict__ dvec,
    float* __restrict__ S, float* __restrict__ LAb, float* __restrict__ y)
{
  int c = blockIdx.x, h = blockIdx.y, b = blockIdx.z;
  int t = threadIdx.x, w = t >> 6, lane = t & 63;
  int quad = lane >> 4, l16 = lane & 15;
  int l0 = c*QCH;
  __shared__ unsigned short XT[64*40];    // XT[p][j] = X[j][p]
  __shared__ unsigned short BTc[128*40];  // BTc[n][j] = coef[j]*B[j][n]
  __shared__ unsigned short Bb[32*136];   // B[j][n]
  __shared__ unsigned short Cb[32*136];   // C[i][n]
  __shared__ unsigned short Gb[32*40];    // G[i][j]
  __shared__ float dtl[32], lal[32], coef[32];
  float A  = -__expf(alog[h]);
  float Dv = dvec[h];

  // prefetch globals into regs (overlaps with dt prefix chain)
  float xv[8];
  #pragma unroll
  for (int k = 0; k < 8; k++){
    int idx = t + k*256; int j = idx >> 6, p = idx & 63;
    xv[k] = xc[(long)(b*L_SEQ + l0 + j)*CONVD + h*64 + p];
  }
  float bv[16], cv[16];
  #pragma unroll
  for (int k = 0; k < 16; k++){
    int idx = t + k*256; int j = idx >> 7, n = idx & 127;
    long rb = (long)(b*L_SEQ + l0 + j)*CONVD + DINNER;
    bv[k] = xc[rb + n];
    cv[k] = xc[rb + DSTATE + n];
  }
  if (t < 32) dtl[t] = dtbuf[(b*L_SEQ + l0 + t)*NHEADSM + h];
  __syncthreads();
  if (t == 0){ float s = 0.f; for (int i = 0; i < 32; i++){ s += dtl[i]; lal[i] = s*A; } }
  __syncthreads();
  if (t < 32){
    coef[t] = __expf(lal[31] - lal[t]) * dtl[t];
    LAb[(b*NHEADSM + h)*L_SEQ + l0 + t] = lal[t];
  }
  __syncthreads();
  #pragma unroll
  for (int k = 0; k < 8; k++){
    int idx = t + k*256; int j = idx >> 6, p = idx & 63;
    XT[p*40 + j] = f2b(xv[k]);
  }
  #pragma unroll
  for (int k = 0; k < 16; k++){
    int idx = t + k*256; int j = idx >> 7, n = idx & 127;
    Bb[j*136 + n] = f2b(bv[k]);
    Cb[j*136 + n] = f2b(cv[k]);
    BTc[n*40 + j] = f2b(bv[k] * coef[j]);
  }
  __syncthreads();

  // ---- S: wave w owns p-block w; 8 n-blocks ----
  short8 afS = *(const short8*)&XT[(w*16 + l16)*40 + quad*8];
  floatx4 accS[8];
  #pragma unroll
  for (int nb = 0; nb < 8; nb++){
    short8 bfS = *(const short8*)&BTc[(nb*16 + l16)*40 + quad*8];
    accS[nb] = __builtin_amdgcn_mfma_f32_16x16x32_bf16(afS, bfS, (floatx4){0.f,0.f,0.f,0.f}, 0, 0, 0);
  }
  // ---- G: wave w -> (ti = w&1, tj = w>>1) ----
  int ti = w & 1, tj = w >> 1;
  floatx4 accG = (floatx4){0.f,0.f,0.f,0.f};
  #pragma unroll
  for (int ks = 0; ks < 4; ks++){
    short8 ga = *(const short8*)&Cb[(ti*16 + l16)*136 + ks*32 + quad*8];
    short8 gb = *(const short8*)&Bb[(tj*16 + l16)*136 + ks*32 + quad*8];
    accG = __builtin_amdgcn_mfma_f32_16x16x32_bf16(ga, gb, accG, 0, 0, 0);
  }
  // store S (C-layout: row=quad*4+rr, col=l16)
  long sb = ((long)((b*NHEADSM + h)*NCH + c))*8192;
  #pragma unroll
  for (int nb = 0; nb < 8; nb++)
    #pragma unroll
    for (int rr = 0; rr < 4; rr++)
      S[sb + (w*16 + quad*4 + rr)*128 + nb*16 + l16] = accS[nb][rr];
  // mask/exp G, write bf16
  #pragma unroll
  for (int rr = 0; rr < 4; rr++){
    int i = ti*16 + quad*4 + rr, j = tj*16 + l16;
    float g = (j <= i) ? __expf(lal[i] - lal[j]) * dtl[j] * accG[rr] : 0.f;
    Gb[i*40 + j] = f2b(g);
  }
  __syncthreads();
  // ---- Y: wave w -> (ti = w&1, pb = (w>>1)*2 + s) ----
  short8 ag = *(const short8*)&Gb[(ti*16 + l16)*40 + quad*8];
  #pragma unroll
  for (int s = 0; s < 2; s++){
    int pb = (w >> 1)*2 + s;
    short8 bx = *(const short8*)&XT[(pb*16 + l16)*40 + quad*8];
    floatx4 accY = __builtin_amdgcn_mfma_f32_16x16x32_bf16(ag, bx, (floatx4){0.f,0.f,0.f,0.f}, 0, 0, 0);
    #pragma unroll
    for (int rr = 0; rr < 4; rr++){
      int i = ti*16 + quad*4 + rr, p = pb*16 + l16;
      float xval = b2f(XT[p*40 + i]);
      y[(long)(b*L_SEQ + l0 + i)*DINNER + h*64 + p] = fmaf(Dv, xval, accY[rr]);
    }
  }
}

// chunk2: state propagation, IN-PLACE, one thread per state element.
__global__ __launch_bounds__(256) void k_chunk2(
    float* __restrict__ S, const float* __restrict__ LAb)
{
  int bh = blockIdx.x >> 5;
  int e = ((blockIdx.x & 31) << 8) + threadIdx.x;
  long base = (long)bh*NCH*8192 + e;
  int laBase = bh*L_SEQ;
  float lam[NCH];
  #pragma unroll
  for (int c = 0; c < NCH; c++) lam[c] = __expf(LAb[laBase + c*QCH + QCH - 1]);
  float hr = 0.f;
  #pragma unroll
  for (int c = 0; c < NCH; c++){
    long off = base + (long)c*8192;
    float sv = S[off];
    S[off] = hr;
    hr = fmaf(hr, lam[c], sv);
  }
}

// chunk3: Y += exp(la_i) * C.H^T  [32x64, K=128] via MFMA; H double-bf16.
__global__ __launch_bounds__(256) void k_chunk3(
    const float* __restrict__ xc, const float* __restrict__ H,
    const float* __restrict__ LAb, float* __restrict__ y)
{
  int c = blockIdx.x, h = blockIdx.y, b = blockIdx.z;
  int t = threadIdx.x, w = t >> 6, lane = t & 63;
  int quad = lane >> 4, l16 = lane & 15;
  int l0 = c*QCH;
  __shared__ unsigned short Cb[32*136];
  __shared__ unsigned short Hhi[64*136];
  __shared__ unsigned short Hlo[64*136];
  __shared__ float el[32];
  if (t < 32) el[t] = __expf(LAb[(b*NHEADSM + h)*L_SEQ + l0 + t]);
  #pragma unroll
  for (int k = 0; k < 16; k++){
    int idx = t + k*256; int j = idx >> 7, n = idx & 127;
    Cb[j*136 + n] = f2b(xc[(long)(b*L_SEQ + l0 + j)*CONVD + DINNER + DSTATE + n]);
  }
  long hb = ((long)((b*NHEADSM + h)*NCH + c))*8192;
  #pragma unroll
  for (int k = 0; k < 32; k++){
    int idx = t + k*256; int p = idx >> 7, n = idx & 127;
    float v = H[hb + idx];
    unsigned short hi = f2b(v);
    Hhi[p*136 + n] = hi;
    Hlo[p*136 + n] = f2b(v - b2f(hi));
  }
  __syncthreads();
  int ti = w & 1;
  #pragma unroll
  for (int s = 0; s < 2; s++){
    int pb = (w >> 1)*2 + s;
    floatx4 acc = (floatx4){0.f,0.f,0.f,0.f};
    #pragma unroll
    for (int ks = 0; ks < 4; ks++){
      short8 a  = *(const short8*)&Cb [(ti*16 + l16)*136 + ks*32 + quad*8];
      short8 bl = *(const short8*)&Hlo[(pb*16 + l16)*136 + ks*32 + quad*8];
      short8 bh = *(const short8*)&Hhi[(pb*16 + l16)*136 + ks*32 + quad*8];
      acc = __builtin_amdgcn_mfma_f32_16x16x32_bf16(a, bl, acc, 0, 0, 0);
      acc = __builtin_amdgcn_mfma_f32_16x16x32_bf16(a, bh, acc, 0, 0, 0);
    }
    #pragma unroll
    for (int rr = 0; rr < 4; rr++){
      int i = ti*16 + quad*4 + rr, p = pb*16 + l16;
      long yb = (long)(b*L_SEQ + l0 + i)*DINNER + h*64 + p;
      y[yb] = fmaf(el[i], acc[rr], y[yb]);
    }
  }
}

__global__ __launch_bounds__(256) void k_gated_rms(
    const float* __restrict__ y, const float* __restrict__ zx, const float* __restrict__ rw,
    unsigned short* __restrict__ ybf)
{
  int r = blockIdx.x, t = threadIdx.x;
  float g[4]; float ss = 0.f;
  #pragma unroll
  for (int i = 0; i < 4; i++){
    int c = t + i*256;
    float z  = zx[(long)r*DINPROJ + c];
    float yv = y[(long)r*DINNER + c];
    float gz = z / (1.f + __expf(-z));
    g[i] = yv * gz;
    ss = fmaf(g[i], g[i], ss);
  }
  #pragma unroll
  for (int o = 1; o < 64; o <<= 1) ss += __shfl_xor(ss, o);
  __shared__ float red[4];
  int w = t >> 6, lane = t & 63;
  if (lane == 0) red[w] = ss;
  __syncthreads();
  float tot = red[0] + red[1] + red[2] + red[3];
  float sc = rsqrtf(tot / (float)DINNER + 1e-5f);
  #pragma unroll
  for (int i = 0; i < 4; i++){
    int c = t + i*256;
    ybf[(long)r*DINNER + c] = f2b(g[i] * sc * rw[c]);
  }
}

__global__ __launch_bounds__(256) void k_add_ln(
    float* __restrict__ x, const float* __restrict__ o,
    const float* __restrict__ lw, const float* __restrict__ lb,
    unsigned short* __restrict__ xbf)
{
  int r = blockIdx.x, t = threadIdx.x;
  float v[2]; float sm = 0.f;
  #pragma unroll
  for (int i = 0; i < 2; i++){ int c = t + i*256; v[i] = x[(long)r*DMODEL + c] + o[(long)r*DMODEL + c]; sm += v[i]; }
  #pragma unroll
  for (int off = 1; off < 64; off <<= 1) sm += __shfl_xor(sm, off);
  __shared__ float red[4]; __shared__ float red2[4];
  int w = t >> 6, lane = t & 63;
  if (lane == 0) red[w] = sm;
  __syncthreads();
  float mu = (red[0] + red[1] + red[2] + red[3]) / (float)DMODEL;
  float var = 0.f;
  #pragma unroll
  for (int i = 0; i < 2; i++){ v[i] -= mu; var = fmaf(v[i], v[i], var); }
  #pragma unroll
  for (int off = 1; off < 64; off <<= 1) var += __shfl_xor(var, off);
  if (lane == 0) red2[w] = var;
  __syncthreads();
  float vv = (red2[0] + red2[1] + red2[2] + red2[3]) / (float)DMODEL;
  float sc = rsqrtf(vv + 1e-5f);
  #pragma unroll
  for (int i = 0; i < 2; i++){
    int c = t + i*256;
    float ov = v[i]*sc*lw[c] + lb[c];
    x[(long)r*DMODEL + c] = ov;
    xbf[(long)r*DMODEL + c] = f2b(ov);
  }
}

extern "C" void kernel_launch(void* const* d_in, const int* in_sizes, int n_in,
                              void* d_out, int out_size, void* d_ws, size_t ws_size,
                              hipStream_t stream)
{
  const int* tokens = (const int*)d_in[0];
  const void* emb = d_in[1];
  int* flag = (int*)d_ws;
  float* ws = (float*)((char*)d_ws + 256);

  k_detect<<<1, 256, 0, stream>>>((const unsigned*)emb, flag);

  ConvArgs ca;
  const int sizes[9] = {10240, 2560, 32, 32, 32, 2048, 1024, 1024, 1000};
  const int idxs[9]  = {3, 4, 5, 6, 7, 8, 10, 11, 13};
  int off = 0;
  for (int s = 0; s < 9; s++){ ca.src[s] = d_in[idxs[s]]; ca.off[s] = off; off += sizes[s]; }
  ca.off[9] = off;

  float* X  = ws + O_X;
  float* ZX = ws + O_ZX;
  float* XC = ws + O_XC;
  float* DT = ws + O_DT;
  float* Y  = ws + O_Y;
  float* Ob = ws + O_O;
  float* LA = ws + O_LA;
  float* Sb = ws + O_S;
  unsigned short* ub  = (unsigned short*)(ws + O_UB);
  unsigned short* WiB = ub + U_WI;
  unsigned short* WoB = ub + U_WO;
  unsigned short* WhB = ub + U_WH;
  unsigned short* Xbf = ub + U_XBF;
  unsigned short* Ybf = ub + U_YBF;

  k_prep<<<71 + NPREPW + NROWS, 256, 0, stream>>>(
      ca, d_in[2], d_in[9], d_in[12], tokens, emb, flag,
      ws, WiB, WoB, WhB, X, Xbf);

  for (int layer = 0; layer < 2; layer++){
    k_mfma_nt<<<dim3(WI_PAD/64, NROWS/64), 256, 0, stream>>>(
        Xbf, WiB + (long)layer*WI_PAD*DMODEL, (void*)ZX,
        NROWS, DINPROJ, DMODEL, (const float*)nullptr, flag, 0);
    k_conv_dt<<<NROWS, 256, 0, stream>>>(
        ZX, ws + W_CONVW + layer*5120, ws + W_CONVB + layer*1280, ws + W_DTB + layer*16, XC, DT);
    k_chunk1<<<dim3(NCH, NHEADSM, BATCH), 256, 0, stream>>>(
        XC, DT, ws + W_ALOG + layer*16, ws + W_DD + layer*16, Sb, LA, Y);
    k_chunk2<<<1024, 256, 0, stream>>>(Sb, LA);
    k_chunk3<<<dim3(NCH, NHEADSM, BATCH), 256, 0, stream>>>(XC, Sb, LA, Y);
    k_gated_rms<<<NROWS, 256, 0, stream>>>(Y, ZX, ws + W_RMSW + layer*1024, Ybf);
    k_mfma_nt<<<dim3(DMODEL/64, NROWS/64), 256, 0, stream>>>(
        Ybf, WoB + (long)layer*DMODEL*DINNER, (void*)Ob,
        NROWS, DMODEL, DINNER, (const float*)nullptr, flag, 0);
    k_add_ln<<<NROWS, 256, 0, stream>>>(X, Ob, ws + W_LNW + layer*512, ws + W_LNB + layer*512, Xbf);
  }

  k_mfma_nt<<<dim3(WH_PAD/64, NROWS/64), 256, 0, stream>>>(
      Xbf, WhB, d_out, NROWS, 1000, DMODEL, ws + W_HEADB, flag, 1);
}